// Round 5
// baseline (4627.260 us; speedup 1.0000x reference)
//
#include <hip/hip_runtime.h>

#define NEG_INF_F (-1e30f)
#define MAX_S 2048
#define MAX_C 3008
#define NCH   128

// ============================ build helpers (deterministic) ============================

__global__ void zero_kernel(int* __restrict__ p, int n) {
  int i = blockIdx.x * blockDim.x + threadIdx.x;
  if (i < n) p[i] = 0;
}

// per-b histogram (numerator): grid (ceil(A/256), B)
__global__ void hist_kernel(const int* __restrict__ dst, int A, int A_stride,
                            int* __restrict__ cnt, int S) {
  int b = blockIdx.y;
  int i = blockIdx.x * blockDim.x + threadIdx.x;
  if (i < A) atomicAdd(&cnt[b * S + dst[(size_t)b * A_stride + i]], 1);
}

// chunked histogram (denominator): grid NCH blocks
__global__ void hist_chunk_kernel(const int* __restrict__ dst, int A, int chunk, int S,
                                  int* __restrict__ hist) {
  int c = blockIdx.x;
  int i1 = min(A, (c + 1) * chunk);
  for (int i = c * chunk + threadIdx.x; i < i1; i += blockDim.x)
    atomicAdd(&hist[c * S + dst[i]], 1);
}

__global__ void colsum_kernel(const int* __restrict__ hist, int nch, int S,
                              int* __restrict__ cnt) {
  int s = blockIdx.x * blockDim.x + threadIdx.x;
  if (s < S) {
    int t = 0;
    for (int c = 0; c < nch; ++c) t += hist[c * S + s];
    cnt[s] = t;
  }
}

// Stable in-degree rank (desc) -> slot permutation pairing heavy with light.
__global__ __launch_bounds__(1024)
void rank_perm_kernel(const int* __restrict__ cnt, int S,
                      int* __restrict__ perm, int* __restrict__ invperm) {
  __shared__ int c[2048];
  __shared__ int R[2048];
  const int tid = threadIdx.x;
  for (int i = tid; i < 2048; i += 1024) c[i] = (i < S) ? cnt[i] : -1;
  __syncthreads();
  for (int u = 0; u < 2; ++u) {
    int s = tid + u * 1024;
    if (s < S) {
      int cs = c[s], r = 0;
      for (int j = 0; j < S; ++j) {
        int cj = c[j];
        r += (cj > cs) || (cj == cs && j < s);
      }
      R[r] = s;
    }
  }
  __syncthreads();
  for (int u = 0; u < 2; ++u) {
    int slot = tid + u * 1024;
    if (slot < S) {
      int state = (slot < 1024) ? R[slot] : R[S - 1 - (slot - 1024)];
      perm[slot] = state;
      invperm[state] = slot;
    }
  }
}

// padded per-slot counts over 2048 slots
__global__ void pc_kernel(const int* __restrict__ cnt, const int* __restrict__ perm,
                          int S, int* __restrict__ pc) {
  int slot = blockIdx.x * blockDim.x + threadIdx.x;
  if (slot < 2048) pc[slot] = (slot < S) ? ((cnt[perm[slot]] + 3) & ~3) : 0;
}

// numerator: padded counts
__global__ void padcnt_kernel(const int* __restrict__ cnt, int n, int* __restrict__ out) {
  int i = blockIdx.x * blockDim.x + threadIdx.x;
  if (i < n) out[i] = (cnt[i] + 3) & ~3;
}

// grid = nfsa blocks of 1024; counts over S entries (S <= 2048). Exclusive scan -> rp[S+1].
__global__ __launch_bounds__(1024) void scan_kernel(const int* __restrict__ cnt,
                                                    int* __restrict__ rp, int S) {
  __shared__ int buf[2][2048];
  const int tid = threadIdx.x;
  const int b = blockIdx.x;
  const int* c = cnt + (size_t)b * S;
  int* r = rp + (size_t)b * (S + 1);
  for (int u = 0; u < 2; ++u) {
    int i = tid + u * 1024;
    buf[0][i] = (i < S) ? c[i] : 0;
  }
  __syncthreads();
  int cur = 0;
  for (int off = 1; off < 2048; off <<= 1) {
    for (int u = 0; u < 2; ++u) {
      int i = tid + u * 1024;
      buf[cur ^ 1][i] = buf[cur][i] + ((i >= off) ? buf[cur][i - off] : 0);
    }
    __syncthreads();
    cur ^= 1;
  }
  for (int u = 0; u < 2; ++u) {
    int i = tid + u * 1024;
    if (i <= S) r[i] = (i == 0) ? 0 : buf[cur][i - 1];
  }
  if (tid == 0) r[S] = buf[cur][S - 1];
}

// hist[c][state] -> starting write offset for (chunk c, state), rows at rp[slot]
__global__ void off_perm_kernel(int* __restrict__ hist, int nch, int S,
                                const int* __restrict__ rp, const int* __restrict__ perm) {
  int slot = blockIdx.x * blockDim.x + threadIdx.x;
  if (slot < S) {
    int state = perm[slot];
    int run = rp[slot];
    for (int c = 0; c < nch; ++c) {
      int h = hist[c * S + state];
      hist[c * S + state] = run;
      run += h;
    }
  }
}

// fill pad arcs at row tails (den)
__global__ void pad_den_kernel(const int* __restrict__ rp, const int* __restrict__ cnt,
                               const int* __restrict__ perm, int S, uint2* __restrict__ meta) {
  int slot = blockIdx.x * blockDim.x + threadIdx.x;
  if (slot < S) {
    int p = rp[slot] + cnt[perm[slot]];
    int e = rp[slot + 1];
    uint2 pad = make_uint2(0u, __float_as_uint(NEG_INF_F));
    for (; p < e; ++p) meta[p] = pad;
  }
}

// grid (ceil(S/256), NCH): thread (state,c) scans chunk c in original order -> stable CSR.
__global__ void fill_chunk_kernel(const int* __restrict__ src, const int* __restrict__ dst,
                                  const int* __restrict__ pdf, const float* __restrict__ w,
                                  int A, int chunk, int S, int* __restrict__ hoff,
                                  const int* __restrict__ inv, uint2* __restrict__ meta) {
  int c = blockIdx.y;
  int s = blockIdx.x * blockDim.x + threadIdx.x;
  if (s >= S) return;
  int i1 = min(A, (c + 1) * chunk);
  int p = hoff[c * S + s];
  for (int i = c * chunk; i < i1; ++i) {
    if (dst[i] == s) {
      meta[p++] = make_uint2((unsigned)inv[src[i]] | ((unsigned)pdf[i] << 16),
                             __float_as_uint(w[i]));
    }
  }
}

// serial per-state fill + tail pad (numerator, tiny): grid (ceil(S/256), B)
__global__ void fill_kernel(const int* __restrict__ src, const int* __restrict__ dst,
                            const int* __restrict__ pdf, const float* __restrict__ w,
                            int A, int A_stride, const int* __restrict__ rp, int S,
                            uint2* __restrict__ meta, int meta_stride) {
  int b = blockIdx.y;
  int s = blockIdx.x * blockDim.x + threadIdx.x;
  if (s >= S) return;
  const int*   sb = src + (size_t)b * A_stride;
  const int*   db = dst + (size_t)b * A_stride;
  const int*   pb = pdf + (size_t)b * A_stride;
  const float* wb = w   + (size_t)b * A_stride;
  const int*   rpb = rp + (size_t)b * (S + 1);
  uint2* mb = meta + (size_t)b * meta_stride;
  int p = rpb[s];
  for (int i = 0; i < A; ++i) {
    if (db[i] == s) {
      mb[p++] = make_uint2((unsigned)sb[i] | ((unsigned)pb[i] << 16), __float_as_uint(wb[i]));
    }
  }
  uint2 pad = make_uint2(0u, __float_as_uint(NEG_INF_F));
  int e = rpb[s + 1];
  for (; p < e; ++p) mb[p] = pad;
}

// ============================ shared row-LSE (identical numerics to round 4) ============================

__device__ __forceinline__ float row_lse(const uint2* __restrict__ meta, int k, int e,
                                         const float* __restrict__ alpha,
                                         const float* __restrict__ lcur) {
  float mm0 = NEG_INF_F, ss0 = 0.0f, mm1 = NEG_INF_F, ss1 = 0.0f;
  const int n4 = (e - k) >> 2;
  const uint4* p = (const uint4*)(meta + k);
  if (n4 > 0) {
    uint4 A = p[0], Bv = p[1];
    float t0 = alpha[A.x & 0xFFFFu] + __uint_as_float(A.y) + lcur[A.x >> 16];
    float t1 = alpha[A.z & 0xFFFFu] + __uint_as_float(A.w) + lcur[A.z >> 16];
    float t2 = alpha[Bv.x & 0xFFFFu] + __uint_as_float(Bv.y) + lcur[Bv.x >> 16];
    float t3 = alpha[Bv.z & 0xFFFFu] + __uint_as_float(Bv.w) + lcur[Bv.z >> 16];
    for (int c2 = 1; c2 < n4; ++c2) {
      uint4 A2 = p[2 * c2], B2 = p[2 * c2 + 1];
      float u0 = alpha[A2.x & 0xFFFFu] + __uint_as_float(A2.y) + lcur[A2.x >> 16];
      float u1 = alpha[A2.z & 0xFFFFu] + __uint_as_float(A2.w) + lcur[A2.z >> 16];
      float u2 = alpha[B2.x & 0xFFFFu] + __uint_as_float(B2.y) + lcur[B2.x >> 16];
      float u3 = alpha[B2.z & 0xFFFFu] + __uint_as_float(B2.w) + lcur[B2.z >> 16];
      float mc = fmaxf(fmaxf(t0, t1), fmaxf(t2, t3));
      if ((c2 & 1) != 0) {
        float nm = fmaxf(mm0, mc);
        ss0 = ss0 * __expf(mm0 - nm) +
              ((__expf(t0 - nm) + __expf(t1 - nm)) + (__expf(t2 - nm) + __expf(t3 - nm)));
        mm0 = nm;
      } else {
        float nm = fmaxf(mm1, mc);
        ss1 = ss1 * __expf(mm1 - nm) +
              ((__expf(t0 - nm) + __expf(t1 - nm)) + (__expf(t2 - nm) + __expf(t3 - nm)));
        mm1 = nm;
      }
      t0 = u0; t1 = u1; t2 = u2; t3 = u3;
    }
    float mc = fmaxf(fmaxf(t0, t1), fmaxf(t2, t3));
    if ((n4 & 1) != 0) {
      float nm = fmaxf(mm0, mc);
      ss0 = ss0 * __expf(mm0 - nm) +
            ((__expf(t0 - nm) + __expf(t1 - nm)) + (__expf(t2 - nm) + __expf(t3 - nm)));
      mm0 = nm;
    } else {
      float nm = fmaxf(mm1, mc);
      ss1 = ss1 * __expf(mm1 - nm) +
            ((__expf(t0 - nm) + __expf(t1 - nm)) + (__expf(t2 - nm) + __expf(t3 - nm)));
      mm1 = nm;
    }
  }
  float nm = fmaxf(mm0, mm1);
  float ssc = ss0 * __expf(mm0 - nm) + ss1 * __expf(mm1 - nm);
  return (ssc > 0.0f) ? (__logf(ssc) + nm) : NEG_INF_F;
}

__device__ __forceinline__ void stage_row(const float* __restrict__ row,
                                          float* __restrict__ lds, int C, int tid, int nt) {
  if (((C & 3) == 0) && ((((uintptr_t)row) & 15) == 0)) {
    const float4* r4 = (const float4*)row;
    const int n = C >> 2;
    for (int i = tid; i < n; i += nt) ((float4*)lds)[i] = r4[i];
  } else {
    for (int i = tid; i < C; i += nt) lds[i] = row[i];
  }
}

// ============================ split forward ============================
// Den: NSPLIT blocks per chain; block k of chain b = blockIdx k*B + b (same-XCD when B%8==0).
// Each block holds full alpha+llrow in LDS, computes pair slots (k*256+i, 2047-that),
// exchanges slices through double-buffered global alpha + per-chain arrival counter.
// Num: 1 block per chain (blockIdx NSPLIT*B + b), LDS-only.
template<int NSPLIT>
__global__ __launch_bounds__(256)
void fsa_forward_split(const float* __restrict__ ll, const int* __restrict__ seqlen,
                       const uint2* __restrict__ den_meta, const int* __restrict__ den_rp,
                       const int* __restrict__ den_perm, int S_den,
                       const uint2* __restrict__ num_meta, const int* __restrict__ num_rp,
                       int num_stride, int S_num,
                       const float* __restrict__ den_init, const float* __restrict__ den_final,
                       const float* __restrict__ num_init, const float* __restrict__ num_final,
                       int T, int C, int B,
                       float* __restrict__ alphaG,  // [B][2][2048]
                       int* __restrict__ bar,       // [B], zeroed per launch
                       float* __restrict__ out_llh)
{
  __shared__ float alpha[MAX_S];
  __shared__ float llrow[MAX_C];
  __shared__ float redbuf[8];

  const int tid = threadIdx.x;
  const int nt  = 256;
  const int bid = (int)blockIdx.x;
  const bool is_den = bid < NSPLIT * B;
  const int b = is_den ? (bid % B) : (bid - NSPLIT * B);
  const int k = is_den ? (bid / B) : 0;

  const int S = is_den ? S_den : S_num;
  const float* init = is_den ? den_init  : num_init;
  const float* fin  = is_den ? den_final : num_final;
  const int*   perm = is_den ? den_perm  : nullptr;

  // full alpha in LDS
  for (int s = tid; s < MAX_S; s += nt)
    alpha[s] = (s < S) ? init[perm ? perm[s] : s] : NEG_INF_F;

  const int L = seqlen[b];
  const float* llb = ll + ((size_t)b * T) * C;
  __syncthreads();

  if (L > 0) stage_row(llb, llrow, C, tid, nt);
  __syncthreads();

  if (is_den) {
    const int slotA = k * nt + tid;          // [0,1024)
    const int slotB = 2047 - slotA;          // [1024,2048): heavy-light pair
    const int rA0 = den_rp[slotA], rA1 = den_rp[slotA + 1];
    const int rB0 = den_rp[slotB], rB1 = den_rp[slotB + 1];

    for (int t = 0; t < L; ++t) {
      float nvA = row_lse(den_meta, rA0, rA1, alpha, llrow);
      float nvB = row_lse(den_meta, rB0, rB1, alpha, llrow);
      __syncthreads();                       // done reading alpha + llrow

      float* aw = alphaG + (((size_t)b * 2 + ((t + 1) & 1)) << 11);
      __hip_atomic_store(&aw[slotA], nvA, __ATOMIC_RELAXED, __HIP_MEMORY_SCOPE_AGENT);
      __hip_atomic_store(&aw[slotB], nvB, __ATOMIC_RELAXED, __HIP_MEMORY_SCOPE_AGENT);

      if (t + 1 < L) stage_row(llb + (size_t)(t + 1) * C, llrow, C, tid, nt);

      __syncthreads();                       // drains stores (vmcnt) before arrival
      if (tid == 0) {
        __hip_atomic_fetch_add(&bar[b], 1, __ATOMIC_RELAXED, __HIP_MEMORY_SCOPE_AGENT);
        while (__hip_atomic_load(&bar[b], __ATOMIC_RELAXED, __HIP_MEMORY_SCOPE_AGENT) <
               NSPLIT * (t + 1)) {
          __builtin_amdgcn_s_sleep(1);
        }
      }
      __syncthreads();
      for (int s = tid; s < MAX_S; s += nt)
        alpha[s] = __hip_atomic_load(&aw[s], __ATOMIC_RELAXED, __HIP_MEMORY_SCOPE_AGENT);
      __syncthreads();
    }
    if (k != 0) return;                      // slice 0 does the final reduction
  } else {
    // numerator: single block, up to 8 slots/thread, all-LDS
    const uint2* meta = num_meta + (size_t)b * num_stride;
    const int*   rp   = num_rp + (size_t)b * (S_num + 1);
    int rs[8], re[8];
#pragma unroll
    for (int u = 0; u < 8; ++u) {
      int slot = tid + u * nt;
      rs[u] = (slot < S) ? rp[slot] : 0;
      re[u] = (slot < S) ? rp[slot + 1] : 0;
    }
    for (int t = 0; t < L; ++t) {
      float nv[8];
#pragma unroll
      for (int u = 0; u < 8; ++u)
        nv[u] = (re[u] > rs[u]) ? row_lse(meta, rs[u], re[u], alpha, llrow) : NEG_INF_F;
      __syncthreads();                       // done reading alpha + llrow
      if (t + 1 < L) stage_row(llb + (size_t)(t + 1) * C, llrow, C, tid, nt);
#pragma unroll
      for (int u = 0; u < 8; ++u) {
        int slot = tid + u * nt;
        if (slot < S) alpha[slot] = nv[u];
      }
      __syncthreads();
    }
  }

  // final logsumexp(alpha + final_logp), 256 threads (4 waves)
  float lm = -3.0e38f;
  for (int s = tid; s < S; s += nt) lm = fmaxf(lm, alpha[s] + fin[perm ? perm[s] : s]);
  for (int off = 32; off; off >>= 1) lm = fmaxf(lm, __shfl_down(lm, off));
  if ((tid & 63) == 0) redbuf[tid >> 6] = lm;
  __syncthreads();
  if (tid < 64) {
    float v = (tid < 4) ? redbuf[tid] : -3.0e38f;
    for (int off = 32; off; off >>= 1) v = fmaxf(v, __shfl_down(v, off));
    if (tid == 0) redbuf[0] = v;
  }
  __syncthreads();
  const float M = redbuf[0];

  float ls = 0.0f;
  for (int s = tid; s < S; s += nt) ls += __expf(alpha[s] + fin[perm ? perm[s] : s] - M);
  for (int off = 32; off; off >>= 1) ls += __shfl_down(ls, off);
  __syncthreads();
  if ((tid & 63) == 0) redbuf[tid >> 6] = ls;
  __syncthreads();
  if (tid < 64) {
    float v = (tid < 4) ? redbuf[tid] : 0.0f;
    for (int off = 32; off; off >>= 1) v += __shfl_down(v, off);
    if (tid == 0) out_llh[(is_den ? 0 : B) + b] = __logf(v) + M;
  }
}

// ============================ single-block CSR forward (round-4, fallback) ============================
__global__ __launch_bounds__(1024)
void fsa_forward_csr3(const float* __restrict__ ll, const int* __restrict__ seqlen,
                      const uint2* __restrict__ den_meta, const int* __restrict__ den_rp,
                      const int* __restrict__ den_perm, int S_den,
                      const uint2* __restrict__ num_meta, const int* __restrict__ num_rp,
                      int num_stride, int S_num,
                      const float* __restrict__ den_init, const float* __restrict__ den_final,
                      const float* __restrict__ num_init, const float* __restrict__ num_final,
                      int T, int C, int B, float* __restrict__ out_llh)
{
  __shared__ float alpha[MAX_S];
  __shared__ float llrow[MAX_C];
  __shared__ float redbuf[16];

  const int tid = threadIdx.x;
  const int nt  = blockDim.x;
  const bool is_den = ((int)blockIdx.x) < B;
  const int b = is_den ? (int)blockIdx.x : ((int)blockIdx.x - B);
  const int S = is_den ? S_den : S_num;
  const float* init = is_den ? den_init  : num_init;
  const float* fin  = is_den ? den_final : num_final;
  const uint2* meta = is_den ? den_meta : (num_meta + (size_t)b * num_stride);
  const int*   rp   = is_den ? den_rp   : (num_rp   + (size_t)b * (S_num + 1));
  const int*   perm = is_den ? den_perm : nullptr;

  for (int s = tid; s < S; s += nt) alpha[s] = init[perm ? perm[s] : s];

  int rs[2] = {0, 0}, re[2] = {0, 0};
  for (int u = 0; u < 2; ++u) {
    int s = tid + u * nt;
    if (s < S) { rs[u] = rp[s]; re[u] = rp[s + 1]; }
  }

  const int L = seqlen[b];
  const float* llb = ll + ((size_t)b * T) * C;
  __syncthreads();

  for (int t = 0; t < L; ++t) {
    stage_row(llb + (size_t)t * C, llrow, C, tid, nt);
    __syncthreads();
    float nv[2];
    for (int u = 0; u < 2; ++u) {
      int s = tid + u * nt;
      nv[u] = (s < S) ? row_lse(meta, rs[u], re[u], alpha, llrow) : NEG_INF_F;
    }
    __syncthreads();
    for (int u = 0; u < 2; ++u) {
      int s = tid + u * nt;
      if (s < S) alpha[s] = nv[u];
    }
    __syncthreads();
  }

  const int nwaves = nt >> 6;
  float lm = -3.0e38f;
  for (int s = tid; s < S; s += nt) lm = fmaxf(lm, alpha[s] + fin[perm ? perm[s] : s]);
  for (int off = 32; off; off >>= 1) lm = fmaxf(lm, __shfl_down(lm, off));
  if ((tid & 63) == 0) redbuf[tid >> 6] = lm;
  __syncthreads();
  if (tid < 64) {
    float v = (tid < nwaves) ? redbuf[tid] : -3.0e38f;
    for (int off = 32; off; off >>= 1) v = fmaxf(v, __shfl_down(v, off));
    if (tid == 0) redbuf[0] = v;
  }
  __syncthreads();
  const float M = redbuf[0];

  float ls = 0.0f;
  for (int s = tid; s < S; s += nt) ls += __expf(alpha[s] + fin[perm ? perm[s] : s] - M);
  for (int off = 32; off; off >>= 1) ls += __shfl_down(ls, off);
  __syncthreads();
  if ((tid & 63) == 0) redbuf[tid >> 6] = ls;
  __syncthreads();
  if (tid < 64) {
    float v = (tid < nwaves) ? redbuf[tid] : 0.0f;
    for (int off = 32; off; off >>= 1) v += __shfl_down(v, off);
    if (tid == 0) out_llh[(is_den ? 0 : B) + b] = __logf(v) + M;
  }
}

// ============================ fallback (atomic path, tiny ws) ============================

__device__ __forceinline__ unsigned enc_f(float x) {
  unsigned u = __float_as_uint(x);
  return u ^ (unsigned)(((int)u >> 31) | 0x80000000);
}
__device__ __forceinline__ float dec_f(unsigned e) {
  unsigned mask = ((int)e >= 0) ? 0xFFFFFFFFu : 0x80000000u;
  return __uint_as_float(e ^ mask);
}

__global__ __launch_bounds__(1024)
void fsa_forward_fallback(
    const float* __restrict__ ll, const int* __restrict__ seqlen,
    const int* __restrict__ den_src, const int* __restrict__ den_dst,
    const int* __restrict__ den_pdf, const float* __restrict__ den_w,
    int A_den, const float* __restrict__ den_init, const float* __restrict__ den_final, int S_den,
    const int* __restrict__ num_src, const int* __restrict__ num_dst,
    const int* __restrict__ num_pdf, const float* __restrict__ num_w,
    int A_num, const float* __restrict__ num_init, const float* __restrict__ num_final, int S_num,
    int T, int C, int B, float* __restrict__ out_llh)
{
  __shared__ float    alpha[MAX_S];
  __shared__ unsigned menc[MAX_S];
  __shared__ float    msafe[MAX_S];
  __shared__ float    ssum[MAX_S];
  __shared__ float    llrow[MAX_C];

  const int tid = threadIdx.x;
  const int nt  = blockDim.x;
  const bool is_den = ((int)blockIdx.x) < B;
  const int b = is_den ? (int)blockIdx.x : ((int)blockIdx.x - B);
  const int S = is_den ? S_den : S_num;
  const int A = is_den ? A_den : A_num;
  const float* init = is_den ? den_init  : num_init;
  const float* fin  = is_den ? den_final : num_final;
  const int*   asrc = is_den ? den_src  : (num_src + (size_t)b * A_num);
  const int*   adst = is_den ? den_dst  : (num_dst + (size_t)b * A_num);
  const int*   apdf = is_den ? den_pdf  : (num_pdf + (size_t)b * A_num);
  const float* aw   = is_den ? den_w    : (num_w   + (size_t)b * A_num);

  for (int s = tid; s < S; s += nt) { alpha[s] = init[s]; menc[s] = 0u; ssum[s] = 0.0f; }
  __syncthreads();

  const int L = seqlen[b];
  const float* llb = ll + ((size_t)b * T) * C;

  for (int t = 0; t < L; ++t) {
    const float* row = llb + (size_t)t * C;
    for (int i = tid; i < C; i += nt) llrow[i] = row[i];
    __syncthreads();
    for (int i = tid; i < A; i += nt) {
      float score = alpha[asrc[i]] + aw[i] + llrow[apdf[i]];
      atomicMax(&menc[adst[i]], enc_f(score));
    }
    __syncthreads();
    for (int s = tid; s < S; s += nt) {
      float m = dec_f(menc[s]);
      msafe[s] = (m > -5e29f) ? m : 0.0f;
    }
    __syncthreads();
    for (int i = tid; i < A; i += nt) {
      int d = adst[i];
      float score = alpha[asrc[i]] + aw[i] + llrow[apdf[i]];
      atomicAdd(&ssum[d], __expf(score - msafe[d]));
    }
    __syncthreads();
    for (int s = tid; s < S; s += nt) {
      float sum = ssum[s];
      alpha[s] = (sum > 0.0f) ? (__logf(sum) + msafe[s]) : NEG_INF_F;
      menc[s] = 0u; ssum[s] = 0.0f;
    }
    __syncthreads();
  }

  float lm = -3.0e38f;
  for (int s = tid; s < S; s += nt) lm = fmaxf(lm, alpha[s] + fin[s]);
  for (int off = 32; off; off >>= 1) lm = fmaxf(lm, __shfl_down(lm, off));
  const int nwaves = nt >> 6;
  if ((tid & 63) == 0) msafe[tid >> 6] = lm;
  __syncthreads();
  if (tid < 64) {
    float v = (tid < nwaves) ? msafe[tid] : -3.0e38f;
    for (int off = 32; off; off >>= 1) v = fmaxf(v, __shfl_down(v, off));
    if (tid == 0) msafe[MAX_S - 1] = v;
  }
  __syncthreads();
  const float M = msafe[MAX_S - 1];
  float ls = 0.0f;
  for (int s = tid; s < S; s += nt) ls += __expf(alpha[s] + fin[s] - M);
  for (int off = 32; off; off >>= 1) ls += __shfl_down(ls, off);
  if ((tid & 63) == 0) ssum[tid >> 6] = ls;
  __syncthreads();
  if (tid < 64) {
    float v = (tid < nwaves) ? ssum[tid] : 0.0f;
    for (int off = 32; off; off >>= 1) v += __shfl_down(v, off);
    if (tid == 0) out_llh[(is_den ? 0 : B) + b] = __logf(v) + M;
  }
}

// loss = sum_b (den_llh[b] - num_llh[b])
__global__ void final_loss_kernel(const float* __restrict__ llh, int B, float* __restrict__ out) {
  int lane = threadIdx.x;
  float v = (lane < B) ? (llh[lane] - llh[B + lane]) : 0.0f;
  for (int off = 32; off; off >>= 1) v += __shfl_down(v, off);
  if (lane == 0) out[0] = v;
}

extern "C" void kernel_launch(void* const* d_in, const int* in_sizes, int n_in,
                              void* d_out, int out_size, void* d_ws, size_t ws_size,
                              hipStream_t stream) {
  const float* ll        = (const float*)d_in[0];
  const int*   seqlen    = (const int*)  d_in[1];
  const int*   num_src   = (const int*)  d_in[2];
  const int*   num_dst   = (const int*)  d_in[3];
  const int*   num_pdf   = (const int*)  d_in[4];
  const float* num_w     = (const float*)d_in[5];
  const float* num_init  = (const float*)d_in[6];
  const float* num_final = (const float*)d_in[7];
  const int*   den_src   = (const int*)  d_in[8];
  const int*   den_dst   = (const int*)  d_in[9];
  const int*   den_pdf   = (const int*)  d_in[10];
  const float* den_w     = (const float*)d_in[11];
  const float* den_init  = (const float*)d_in[12];
  const float* den_final = (const float*)d_in[13];

  const int B     = in_sizes[1];
  const int A_num = in_sizes[2] / B;
  const int S_num = in_sizes[6];
  const int A_den = in_sizes[8];
  const int S_den = in_sizes[12];
  const int T     = 500;                       // problem spec
  const int C     = in_sizes[0] / (B * T);

  const int NSPLIT = 4;
  const int den_cap    = A_den + 3 * S_den + 64;
  const int num_stride = A_num + 3 * S_num + 64;

  // workspace layout
  size_t off = 0;
  auto alloc = [&](size_t bytes, size_t align) -> size_t {
    off = (off + align - 1) / align * align;
    size_t r = off; off += bytes; return r;
  };
  size_t o_den_meta = alloc((size_t)den_cap * 8, 16);
  size_t o_num_meta = alloc((size_t)B * num_stride * 8, 16);
  size_t o_den_rp   = alloc((size_t)2049 * 4, 4);
  size_t o_num_rp   = alloc((size_t)B * (S_num + 1) * 4, 4);
  size_t o_den_cnt  = alloc((size_t)S_den * 4, 4);
  size_t o_perm     = alloc((size_t)2048 * 4, 4);
  size_t o_inv      = alloc((size_t)S_den * 4, 4);
  size_t o_pc       = alloc((size_t)2048 * 4, 4);
  size_t o_num_pc   = alloc((size_t)B * S_num * 4, 4);
  size_t o_hist     = alloc((size_t)NCH * S_den * 4, 4);   // zeroed region start
  size_t o_num_cnt  = alloc((size_t)B * S_num * 4, 4);     // contiguous with hist
  size_t o_bar      = alloc((size_t)B * 4, 4);             // contiguous with num_cnt
  size_t o_llh      = alloc((size_t)2 * B * 4, 4);
  size_t o_alphaG   = alloc((size_t)B * 2 * 2048 * 4, 16);
  const bool use_csr = (o_llh + (size_t)2 * B * 4 <= ws_size) && (S_den >= 1) &&
                       (S_den <= 2048) && (S_num >= 1) && (S_num <= 2048) && (C <= MAX_C);
  const bool use_split = use_csr && (off <= ws_size);

  char* wsb = (char*)d_ws;
  float* llh = (float*)(wsb + (use_csr ? o_llh : 0));

  if (use_csr) {
    uint2* den_meta = (uint2*)(wsb + o_den_meta);
    uint2* num_meta = (uint2*)(wsb + o_num_meta);
    int*   den_rp   = (int*)(wsb + o_den_rp);
    int*   num_rp   = (int*)(wsb + o_num_rp);
    int*   den_cnt  = (int*)(wsb + o_den_cnt);
    int*   perm     = (int*)(wsb + o_perm);
    int*   inv      = (int*)(wsb + o_inv);
    int*   pc       = (int*)(wsb + o_pc);
    int*   num_pc   = (int*)(wsb + o_num_pc);
    int*   hist     = (int*)(wsb + o_hist);
    int*   num_cnt  = (int*)(wsb + o_num_cnt);
    int*   bar      = (int*)(wsb + o_bar);
    float* alphaG   = (float*)(wsb + o_alphaG);

    const int chunk = (A_den + NCH - 1) / NCH;

    // zero hist + num_cnt + bar (contiguous)
    int ztot = NCH * S_den + B * S_num + B;
    zero_kernel<<<(ztot + 255) / 256, 256, 0, stream>>>(hist, ztot);

    hist_chunk_kernel<<<NCH, 256, 0, stream>>>(den_dst, A_den, chunk, S_den, hist);
    hist_kernel<<<dim3((A_num + 255) / 256, B), 256, 0, stream>>>(num_dst, A_num, A_num,
                                                                  num_cnt, S_num);

    colsum_kernel<<<(S_den + 255) / 256, 256, 0, stream>>>(hist, NCH, S_den, den_cnt);
    rank_perm_kernel<<<1, 1024, 0, stream>>>(den_cnt, S_den, perm, inv);
    pc_kernel<<<8, 256, 0, stream>>>(den_cnt, perm, S_den, pc);
    scan_kernel<<<1, 1024, 0, stream>>>(pc, den_rp, 2048);

    padcnt_kernel<<<(B * S_num + 255) / 256, 256, 0, stream>>>(num_cnt, B * S_num, num_pc);
    scan_kernel<<<B, 1024, 0, stream>>>(num_pc, num_rp, S_num);

    off_perm_kernel<<<(S_den + 255) / 256, 256, 0, stream>>>(hist, NCH, S_den, den_rp, perm);
    pad_den_kernel<<<(S_den + 255) / 256, 256, 0, stream>>>(den_rp, den_cnt, perm, S_den, den_meta);
    fill_chunk_kernel<<<dim3((S_den + 255) / 256, NCH), 256, 0, stream>>>(
        den_src, den_dst, den_pdf, den_w, A_den, chunk, S_den, hist, inv, den_meta);
    fill_kernel<<<dim3((S_num + 255) / 256, B), 256, 0, stream>>>(
        num_src, num_dst, num_pdf, num_w, A_num, A_num, num_rp, S_num, num_meta, num_stride);

    if (use_split) {
      fsa_forward_split<4><<<5 * B, 256, 0, stream>>>(
          ll, seqlen, den_meta, den_rp, perm, S_den,
          num_meta, num_rp, num_stride, S_num,
          den_init, den_final, num_init, num_final, T, C, B, alphaG, bar, llh);
    } else {
      fsa_forward_csr3<<<2 * B, 1024, 0, stream>>>(
          ll, seqlen, den_meta, den_rp, perm, S_den,
          num_meta, num_rp, num_stride, S_num,
          den_init, den_final, num_init, num_final, T, C, B, llh);
    }
  } else {
    fsa_forward_fallback<<<2 * B, 1024, 0, stream>>>(
        ll, seqlen,
        den_src, den_dst, den_pdf, den_w, A_den, den_init, den_final, S_den,
        num_src, num_dst, num_pdf, num_w, A_num, num_init, num_final, S_num,
        T, C, B, llh);
  }

  final_loss_kernel<<<1, 64, 0, stream>>>(llh, B, (float*)d_out);
}

// Round 6
// 4414.628 us; speedup vs baseline: 1.0482x; 1.0482x over previous
//
#include <hip/hip_runtime.h>

#define NEG_INF_F (-1e30f)
#define MAX_S 2048
#define MAX_C 3008
#define NCH   128

// ============================ build helpers (deterministic) ============================

__global__ void zero_kernel(int* __restrict__ p, int n) {
  int i = blockIdx.x * blockDim.x + threadIdx.x;
  if (i < n) p[i] = 0;
}

// per-b histogram (numerator): grid (ceil(A/256), B)
__global__ void hist_kernel(const int* __restrict__ dst, int A, int A_stride,
                            int* __restrict__ cnt, int S) {
  int b = blockIdx.y;
  int i = blockIdx.x * blockDim.x + threadIdx.x;
  if (i < A) atomicAdd(&cnt[b * S + dst[(size_t)b * A_stride + i]], 1);
}

// chunked histogram (denominator): grid NCH blocks
__global__ void hist_chunk_kernel(const int* __restrict__ dst, int A, int chunk, int S,
                                  int* __restrict__ hist) {
  int c = blockIdx.x;
  int i1 = min(A, (c + 1) * chunk);
  for (int i = c * chunk + threadIdx.x; i < i1; i += blockDim.x)
    atomicAdd(&hist[c * S + dst[i]], 1);
}

__global__ void colsum_kernel(const int* __restrict__ hist, int nch, int S,
                              int* __restrict__ cnt) {
  int s = blockIdx.x * blockDim.x + threadIdx.x;
  if (s < S) {
    int t = 0;
    for (int c = 0; c < nch; ++c) t += hist[c * S + s];
    cnt[s] = t;
  }
}

// Stable in-degree rank (desc) -> slot permutation pairing heavy with light.
__global__ __launch_bounds__(1024)
void rank_perm_kernel(const int* __restrict__ cnt, int S,
                      int* __restrict__ perm, int* __restrict__ invperm) {
  __shared__ int c[2048];
  __shared__ int R[2048];
  const int tid = threadIdx.x;
  for (int i = tid; i < 2048; i += 1024) c[i] = (i < S) ? cnt[i] : -1;
  __syncthreads();
  for (int u = 0; u < 2; ++u) {
    int s = tid + u * 1024;
    if (s < S) {
      int cs = c[s], r = 0;
      for (int j = 0; j < S; ++j) {
        int cj = c[j];
        r += (cj > cs) || (cj == cs && j < s);
      }
      R[r] = s;
    }
  }
  __syncthreads();
  for (int u = 0; u < 2; ++u) {
    int slot = tid + u * 1024;
    if (slot < S) {
      int state = (slot < 1024) ? R[slot] : R[S - 1 - (slot - 1024)];
      perm[slot] = state;
      invperm[state] = slot;
    }
  }
}

// padded per-slot counts over 2048 slots
__global__ void pc_kernel(const int* __restrict__ cnt, const int* __restrict__ perm,
                          int S, int* __restrict__ pc) {
  int slot = blockIdx.x * blockDim.x + threadIdx.x;
  if (slot < 2048) pc[slot] = (slot < S) ? ((cnt[perm[slot]] + 3) & ~3) : 0;
}

// numerator: padded counts
__global__ void padcnt_kernel(const int* __restrict__ cnt, int n, int* __restrict__ out) {
  int i = blockIdx.x * blockDim.x + threadIdx.x;
  if (i < n) out[i] = (cnt[i] + 3) & ~3;
}

// grid = nfsa blocks of 1024; counts over S entries (S <= 2048). Exclusive scan -> rp[S+1].
__global__ __launch_bounds__(1024) void scan_kernel(const int* __restrict__ cnt,
                                                    int* __restrict__ rp, int S) {
  __shared__ int buf[2][2048];
  const int tid = threadIdx.x;
  const int b = blockIdx.x;
  const int* c = cnt + (size_t)b * S;
  int* r = rp + (size_t)b * (S + 1);
  for (int u = 0; u < 2; ++u) {
    int i = tid + u * 1024;
    buf[0][i] = (i < S) ? c[i] : 0;
  }
  __syncthreads();
  int cur = 0;
  for (int off = 1; off < 2048; off <<= 1) {
    for (int u = 0; u < 2; ++u) {
      int i = tid + u * 1024;
      buf[cur ^ 1][i] = buf[cur][i] + ((i >= off) ? buf[cur][i - off] : 0);
    }
    __syncthreads();
    cur ^= 1;
  }
  for (int u = 0; u < 2; ++u) {
    int i = tid + u * 1024;
    if (i <= S) r[i] = (i == 0) ? 0 : buf[cur][i - 1];
  }
  if (tid == 0) r[S] = buf[cur][S - 1];
}

// hist[c][state] -> starting write offset for (chunk c, state), rows at rp[slot]
__global__ void off_perm_kernel(int* __restrict__ hist, int nch, int S,
                                const int* __restrict__ rp, const int* __restrict__ perm) {
  int slot = blockIdx.x * blockDim.x + threadIdx.x;
  if (slot < S) {
    int state = perm[slot];
    int run = rp[slot];
    for (int c = 0; c < nch; ++c) {
      int h = hist[c * S + state];
      hist[c * S + state] = run;
      run += h;
    }
  }
}

// fill pad arcs at row tails (den): ew = 0 -> term contributes nothing
__global__ void pad_den_kernel(const int* __restrict__ rp, const int* __restrict__ cnt,
                               const int* __restrict__ perm, int S, uint2* __restrict__ meta) {
  int slot = blockIdx.x * blockDim.x + threadIdx.x;
  if (slot < S) {
    int p = rp[slot] + cnt[perm[slot]];
    int e = rp[slot + 1];
    uint2 pad = make_uint2(0u, 0u);
    for (; p < e; ++p) meta[p] = pad;
  }
}

// grid (ceil(S/256), NCH): thread (state,c) scans chunk c in original order -> stable CSR.
// DEN meta stores exp(w) (linear-space weight), src rewritten to slot space.
__global__ void fill_chunk_kernel(const int* __restrict__ src, const int* __restrict__ dst,
                                  const int* __restrict__ pdf, const float* __restrict__ w,
                                  int A, int chunk, int S, int* __restrict__ hoff,
                                  const int* __restrict__ inv, uint2* __restrict__ meta) {
  int c = blockIdx.y;
  int s = blockIdx.x * blockDim.x + threadIdx.x;
  if (s >= S) return;
  int i1 = min(A, (c + 1) * chunk);
  int p = hoff[c * S + s];
  for (int i = c * chunk; i < i1; ++i) {
    if (dst[i] == s) {
      meta[p++] = make_uint2((unsigned)inv[src[i]] | ((unsigned)pdf[i] << 16),
                             __float_as_uint(__expf(w[i])));
    }
  }
}

// serial per-state fill + tail pad (numerator, raw w, tiny): grid (ceil(S/256), B)
__global__ void fill_kernel(const int* __restrict__ src, const int* __restrict__ dst,
                            const int* __restrict__ pdf, const float* __restrict__ w,
                            int A, int A_stride, const int* __restrict__ rp, int S,
                            uint2* __restrict__ meta, int meta_stride) {
  int b = blockIdx.y;
  int s = blockIdx.x * blockDim.x + threadIdx.x;
  if (s >= S) return;
  const int*   sb = src + (size_t)b * A_stride;
  const int*   db = dst + (size_t)b * A_stride;
  const int*   pb = pdf + (size_t)b * A_stride;
  const float* wb = w   + (size_t)b * A_stride;
  const int*   rpb = rp + (size_t)b * (S + 1);
  uint2* mb = meta + (size_t)b * meta_stride;
  int p = rpb[s];
  for (int i = 0; i < A; ++i) {
    if (db[i] == s) {
      mb[p++] = make_uint2((unsigned)sb[i] | ((unsigned)pb[i] << 16), __float_as_uint(wb[i]));
    }
  }
  uint2 pad = make_uint2(0u, __float_as_uint(NEG_INF_F));
  int e = rpb[s + 1];
  for (; p < e; ++p) mb[p] = pad;
}

// ============================ exact row LSE (numerator path) ============================

__device__ __forceinline__ float row_lse(const uint2* __restrict__ meta, int k, int e,
                                         const float* __restrict__ alpha,
                                         const float* __restrict__ lcur) {
  float mm0 = NEG_INF_F, ss0 = 0.0f, mm1 = NEG_INF_F, ss1 = 0.0f;
  const int n4 = (e - k) >> 2;
  const uint4* p = (const uint4*)(meta + k);
  if (n4 > 0) {
    uint4 A = p[0], Bv = p[1];
    float t0 = alpha[A.x & 0xFFFFu] + __uint_as_float(A.y) + lcur[A.x >> 16];
    float t1 = alpha[A.z & 0xFFFFu] + __uint_as_float(A.w) + lcur[A.z >> 16];
    float t2 = alpha[Bv.x & 0xFFFFu] + __uint_as_float(Bv.y) + lcur[Bv.x >> 16];
    float t3 = alpha[Bv.z & 0xFFFFu] + __uint_as_float(Bv.w) + lcur[Bv.z >> 16];
    for (int c2 = 1; c2 < n4; ++c2) {
      uint4 A2 = p[2 * c2], B2 = p[2 * c2 + 1];
      float u0 = alpha[A2.x & 0xFFFFu] + __uint_as_float(A2.y) + lcur[A2.x >> 16];
      float u1 = alpha[A2.z & 0xFFFFu] + __uint_as_float(A2.w) + lcur[A2.z >> 16];
      float u2 = alpha[B2.x & 0xFFFFu] + __uint_as_float(B2.y) + lcur[B2.x >> 16];
      float u3 = alpha[B2.z & 0xFFFFu] + __uint_as_float(B2.w) + lcur[B2.z >> 16];
      float mc = fmaxf(fmaxf(t0, t1), fmaxf(t2, t3));
      if ((c2 & 1) != 0) {
        float nm = fmaxf(mm0, mc);
        ss0 = ss0 * __expf(mm0 - nm) +
              ((__expf(t0 - nm) + __expf(t1 - nm)) + (__expf(t2 - nm) + __expf(t3 - nm)));
        mm0 = nm;
      } else {
        float nm = fmaxf(mm1, mc);
        ss1 = ss1 * __expf(mm1 - nm) +
              ((__expf(t0 - nm) + __expf(t1 - nm)) + (__expf(t2 - nm) + __expf(t3 - nm)));
        mm1 = nm;
      }
      t0 = u0; t1 = u1; t2 = u2; t3 = u3;
    }
    float mc = fmaxf(fmaxf(t0, t1), fmaxf(t2, t3));
    if ((n4 & 1) != 0) {
      float nm = fmaxf(mm0, mc);
      ss0 = ss0 * __expf(mm0 - nm) +
            ((__expf(t0 - nm) + __expf(t1 - nm)) + (__expf(t2 - nm) + __expf(t3 - nm)));
      mm0 = nm;
    } else {
      float nm = fmaxf(mm1, mc);
      ss1 = ss1 * __expf(mm1 - nm) +
            ((__expf(t0 - nm) + __expf(t1 - nm)) + (__expf(t2 - nm) + __expf(t3 - nm)));
      mm1 = nm;
    }
  }
  float nm = fmaxf(mm0, mm1);
  float ssc = ss0 * __expf(mm0 - nm) + ss1 * __expf(mm1 - nm);
  return (ssc > 0.0f) ? (__logf(ssc) + nm) : NEG_INF_F;
}

__device__ __forceinline__ void stage_row(const float* __restrict__ row,
                                          float* __restrict__ lds, int C, int tid, int nt) {
  if (((C & 3) == 0) && ((((uintptr_t)row) & 15) == 0)) {
    const float4* r4 = (const float4*)row;
    const int n = C >> 2;
    for (int i = tid; i < n; i += nt) ((float4*)lds)[i] = r4[i];
  } else {
    for (int i = tid; i < C; i += nt) lds[i] = row[i];
  }
}

// ============================ forward: den linear-space, num exact-LSE ============================
// Blocks [0,B) = denominator chains, [B,2B) = numerator chains. 1024 threads.
__global__ __launch_bounds__(1024)
void fsa_forward_lin(const float* __restrict__ ll, const int* __restrict__ seqlen,
                     const uint2* __restrict__ den_meta, const int* __restrict__ den_rp,
                     const int* __restrict__ den_perm, int S_den,
                     const uint2* __restrict__ num_meta, const int* __restrict__ num_rp,
                     int num_stride, int S_num,
                     const float* __restrict__ den_init, const float* __restrict__ den_final,
                     const float* __restrict__ num_init, const float* __restrict__ num_final,
                     int T, int C, int B, float* __restrict__ out_llh)
{
  __shared__ float alpha[MAX_S];
  __shared__ float vbuf[MAX_S];
  __shared__ float elbuf[MAX_C];   // den: exp(ll) ; num: raw ll
  __shared__ float red[16];

  const int tid = threadIdx.x;
  const int nt  = 1024;
  const bool is_den = ((int)blockIdx.x) < B;
  const int b = is_den ? (int)blockIdx.x : ((int)blockIdx.x - B);
  const int S = is_den ? S_den : S_num;
  const float* fin  = is_den ? den_final : num_final;
  const int*   perm = is_den ? den_perm  : nullptr;

  const int L = seqlen[b];
  const float* llb = ll + ((size_t)b * T) * C;

  if (is_den) {
    // ---- linear-space denominator ----
    const int slotA = tid;            // heavy ranks
    const int slotB = 2047 - tid;     // paired light ranks
    const int rA0 = den_rp[slotA], rA1 = den_rp[slotA + 1];
    const int rB0 = den_rp[slotB], rB1 = den_rp[slotB + 1];
    float a0 = (slotA < S) ? den_init[den_perm[slotA]] : NEG_INF_F;
    float a1 = (slotB < S) ? den_init[den_perm[slotB]] : NEG_INF_F;

    const int nvec = C >> 2;
    const bool pf = ((C & 3) == 0) && ((((uintptr_t)llb) & 15) == 0) &&
                    (nvec <= nt) && (C <= MAX_C);

    // initial M reduce + EL stage for row 0
    float lm = fmaxf(a0, a1);
    for (int off = 32; off; off >>= 1) lm = fmaxf(lm, __shfl_down(lm, off));
    if ((tid & 63) == 0) red[tid >> 6] = lm;
    if (L > 0) {
      if (pf) {
        if (tid < nvec) {
          float4 r = ((const float4*)llb)[tid];
          elbuf[4 * tid + 0] = __expf(r.x); elbuf[4 * tid + 1] = __expf(r.y);
          elbuf[4 * tid + 2] = __expf(r.z); elbuf[4 * tid + 3] = __expf(r.w);
        }
      } else {
        for (int i = tid; i < C; i += nt) elbuf[i] = __expf(llb[i]);
      }
    }
    __syncthreads();
    float M = red[0];
#pragma unroll
    for (int i = 1; i < 16; ++i) M = fmaxf(M, red[i]);

    for (int t = 0; t < L; ++t) {
      vbuf[slotA] = __expf(a0 - M);
      vbuf[slotB] = __expf(a1 - M);
      __syncthreads();                       // v + EL ready

      float4 nx;
      const bool donx = pf && (t + 1 < L) && (tid < nvec);
      if (donx) nx = ((const float4*)(llb + (size_t)(t + 1) * C))[tid];

      // interleaved sparse row sums (8 independent accumulators)
      float sA0 = 0, sA1 = 0, sA2 = 0, sA3 = 0;
      float sB0 = 0, sB1 = 0, sB2 = 0, sB3 = 0;
      const uint4* pA = (const uint4*)(den_meta + rA0);
      const uint4* pB = (const uint4*)(den_meta + rB0);
      const int nA = (rA1 - rA0) >> 2, nB = (rB1 - rB0) >> 2;
      const int n = nA > nB ? nA : nB;
      for (int c = 0; c < n; ++c) {
        if (c < nA) {
          uint4 X = pA[2 * c], Y = pA[2 * c + 1];
          sA0 = fmaf(__uint_as_float(X.y), vbuf[X.x & 0xFFFFu] * elbuf[X.x >> 16], sA0);
          sA1 = fmaf(__uint_as_float(X.w), vbuf[X.z & 0xFFFFu] * elbuf[X.z >> 16], sA1);
          sA2 = fmaf(__uint_as_float(Y.y), vbuf[Y.x & 0xFFFFu] * elbuf[Y.x >> 16], sA2);
          sA3 = fmaf(__uint_as_float(Y.w), vbuf[Y.z & 0xFFFFu] * elbuf[Y.z >> 16], sA3);
        }
        if (c < nB) {
          uint4 X = pB[2 * c], Y = pB[2 * c + 1];
          sB0 = fmaf(__uint_as_float(X.y), vbuf[X.x & 0xFFFFu] * elbuf[X.x >> 16], sB0);
          sB1 = fmaf(__uint_as_float(X.w), vbuf[X.z & 0xFFFFu] * elbuf[X.z >> 16], sB1);
          sB2 = fmaf(__uint_as_float(Y.y), vbuf[Y.x & 0xFFFFu] * elbuf[Y.x >> 16], sB2);
          sB3 = fmaf(__uint_as_float(Y.w), vbuf[Y.z & 0xFFFFu] * elbuf[Y.z >> 16], sB3);
        }
      }
      float sA = (sA0 + sA1) + (sA2 + sA3);
      float sB = (sB0 + sB1) + (sB2 + sB3);
      __syncthreads();                       // done reading vbuf/elbuf

      a0 = (sA > 0.0f) ? (__logf(sA) + M) : NEG_INF_F;
      a1 = (sB > 0.0f) ? (__logf(sB) + M) : NEG_INF_F;

      if (donx) {
        elbuf[4 * tid + 0] = __expf(nx.x); elbuf[4 * tid + 1] = __expf(nx.y);
        elbuf[4 * tid + 2] = __expf(nx.z); elbuf[4 * tid + 3] = __expf(nx.w);
      } else if (!pf && t + 1 < L) {
        const float* nr = llb + (size_t)(t + 1) * C;
        for (int i = tid; i < C; i += nt) elbuf[i] = __expf(nr[i]);
      }

      float lm2 = fmaxf(a0, a1);
      for (int off = 32; off; off >>= 1) lm2 = fmaxf(lm2, __shfl_down(lm2, off));
      if ((tid & 63) == 0) red[tid >> 6] = lm2;
      __syncthreads();                       // red + next EL visible
      M = red[0];
#pragma unroll
      for (int i = 1; i < 16; ++i) M = fmaxf(M, red[i]);
    }
    alpha[slotA] = a0;
    alpha[slotB] = a1;
    __syncthreads();
  } else {
    // ---- exact-LSE numerator (tiny) ----
    const uint2* meta = num_meta + (size_t)b * num_stride;
    const int*   rp   = num_rp + (size_t)b * (S_num + 1);
    for (int s = tid; s < MAX_S; s += nt) alpha[s] = (s < S) ? num_init[s] : NEG_INF_F;
    int rs[2] = {0, 0}, re[2] = {0, 0};
    for (int u = 0; u < 2; ++u) {
      int s = tid + u * nt;
      if (s < S) { rs[u] = rp[s]; re[u] = rp[s + 1]; }
    }
    __syncthreads();
    for (int t = 0; t < L; ++t) {
      stage_row(llb + (size_t)t * C, elbuf, C, tid, nt);
      __syncthreads();
      float nv[2];
      for (int u = 0; u < 2; ++u) {
        int s = tid + u * nt;
        nv[u] = (s < S) ? row_lse(meta, rs[u], re[u], alpha, elbuf) : NEG_INF_F;
      }
      __syncthreads();
      for (int u = 0; u < 2; ++u) {
        int s = tid + u * nt;
        if (s < S) alpha[s] = nv[u];
      }
      __syncthreads();
    }
  }

  // final logsumexp(alpha + final_logp)
  float lm = -3.0e38f;
  for (int s = tid; s < S; s += nt) lm = fmaxf(lm, alpha[s] + fin[perm ? perm[s] : s]);
  for (int off = 32; off; off >>= 1) lm = fmaxf(lm, __shfl_down(lm, off));
  if ((tid & 63) == 0) red[tid >> 6] = lm;
  __syncthreads();
  if (tid < 64) {
    float v = (tid < 16) ? red[tid] : -3.0e38f;
    for (int off = 32; off; off >>= 1) v = fmaxf(v, __shfl_down(v, off));
    if (tid == 0) red[0] = v;
  }
  __syncthreads();
  const float M = red[0];

  float ls = 0.0f;
  for (int s = tid; s < S; s += nt) ls += __expf(alpha[s] + fin[perm ? perm[s] : s] - M);
  for (int off = 32; off; off >>= 1) ls += __shfl_down(ls, off);
  __syncthreads();
  if ((tid & 63) == 0) red[tid >> 6] = ls;
  __syncthreads();
  if (tid < 64) {
    float v = (tid < 16) ? red[tid] : 0.0f;
    for (int off = 32; off; off >>= 1) v += __shfl_down(v, off);
    if (tid == 0) out_llh[(is_den ? 0 : B) + b] = __logf(v) + M;
  }
}

// ============================ fallback (atomic path, tiny ws) ============================

__device__ __forceinline__ unsigned enc_f(float x) {
  unsigned u = __float_as_uint(x);
  return u ^ (unsigned)(((int)u >> 31) | 0x80000000);
}
__device__ __forceinline__ float dec_f(unsigned e) {
  unsigned mask = ((int)e >= 0) ? 0xFFFFFFFFu : 0x80000000u;
  return __uint_as_float(e ^ mask);
}

__global__ __launch_bounds__(1024)
void fsa_forward_fallback(
    const float* __restrict__ ll, const int* __restrict__ seqlen,
    const int* __restrict__ den_src, const int* __restrict__ den_dst,
    const int* __restrict__ den_pdf, const float* __restrict__ den_w,
    int A_den, const float* __restrict__ den_init, const float* __restrict__ den_final, int S_den,
    const int* __restrict__ num_src, const int* __restrict__ num_dst,
    const int* __restrict__ num_pdf, const float* __restrict__ num_w,
    int A_num, const float* __restrict__ num_init, const float* __restrict__ num_final, int S_num,
    int T, int C, int B, float* __restrict__ out_llh)
{
  __shared__ float    alpha[MAX_S];
  __shared__ unsigned menc[MAX_S];
  __shared__ float    msafe[MAX_S];
  __shared__ float    ssum[MAX_S];
  __shared__ float    llrow[MAX_C];

  const int tid = threadIdx.x;
  const int nt  = blockDim.x;
  const bool is_den = ((int)blockIdx.x) < B;
  const int b = is_den ? (int)blockIdx.x : ((int)blockIdx.x - B);
  const int S = is_den ? S_den : S_num;
  const int A = is_den ? A_den : A_num;
  const float* init = is_den ? den_init  : num_init;
  const float* fin  = is_den ? den_final : num_final;
  const int*   asrc = is_den ? den_src  : (num_src + (size_t)b * A_num);
  const int*   adst = is_den ? den_dst  : (num_dst + (size_t)b * A_num);
  const int*   apdf = is_den ? den_pdf  : (num_pdf + (size_t)b * A_num);
  const float* aw   = is_den ? den_w    : (num_w   + (size_t)b * A_num);

  for (int s = tid; s < S; s += nt) { alpha[s] = init[s]; menc[s] = 0u; ssum[s] = 0.0f; }
  __syncthreads();

  const int L = seqlen[b];
  const float* llb = ll + ((size_t)b * T) * C;

  for (int t = 0; t < L; ++t) {
    const float* row = llb + (size_t)t * C;
    for (int i = tid; i < C; i += nt) llrow[i] = row[i];
    __syncthreads();
    for (int i = tid; i < A; i += nt) {
      float score = alpha[asrc[i]] + aw[i] + llrow[apdf[i]];
      atomicMax(&menc[adst[i]], enc_f(score));
    }
    __syncthreads();
    for (int s = tid; s < S; s += nt) {
      float m = dec_f(menc[s]);
      msafe[s] = (m > -5e29f) ? m : 0.0f;
    }
    __syncthreads();
    for (int i = tid; i < A; i += nt) {
      int d = adst[i];
      float score = alpha[asrc[i]] + aw[i] + llrow[apdf[i]];
      atomicAdd(&ssum[d], __expf(score - msafe[d]));
    }
    __syncthreads();
    for (int s = tid; s < S; s += nt) {
      float sum = ssum[s];
      alpha[s] = (sum > 0.0f) ? (__logf(sum) + msafe[s]) : NEG_INF_F;
      menc[s] = 0u; ssum[s] = 0.0f;
    }
    __syncthreads();
  }

  float lm = -3.0e38f;
  for (int s = tid; s < S; s += nt) lm = fmaxf(lm, alpha[s] + fin[s]);
  for (int off = 32; off; off >>= 1) lm = fmaxf(lm, __shfl_down(lm, off));
  const int nwaves = nt >> 6;
  if ((tid & 63) == 0) msafe[tid >> 6] = lm;
  __syncthreads();
  if (tid < 64) {
    float v = (tid < nwaves) ? msafe[tid] : -3.0e38f;
    for (int off = 32; off; off >>= 1) v = fmaxf(v, __shfl_down(v, off));
    if (tid == 0) msafe[MAX_S - 1] = v;
  }
  __syncthreads();
  const float M = msafe[MAX_S - 1];
  float ls = 0.0f;
  for (int s = tid; s < S; s += nt) ls += __expf(alpha[s] + fin[s] - M);
  for (int off = 32; off; off >>= 1) ls += __shfl_down(ls, off);
  if ((tid & 63) == 0) ssum[tid >> 6] = ls;
  __syncthreads();
  if (tid < 64) {
    float v = (tid < nwaves) ? ssum[tid] : 0.0f;
    for (int off = 32; off; off >>= 1) v += __shfl_down(v, off);
    if (tid == 0) out_llh[(is_den ? 0 : B) + b] = __logf(v) + M;
  }
}

// loss = sum_b (den_llh[b] - num_llh[b])
__global__ void final_loss_kernel(const float* __restrict__ llh, int B, float* __restrict__ out) {
  int lane = threadIdx.x;
  float v = (lane < B) ? (llh[lane] - llh[B + lane]) : 0.0f;
  for (int off = 32; off; off >>= 1) v += __shfl_down(v, off);
  if (lane == 0) out[0] = v;
}

extern "C" void kernel_launch(void* const* d_in, const int* in_sizes, int n_in,
                              void* d_out, int out_size, void* d_ws, size_t ws_size,
                              hipStream_t stream) {
  const float* ll        = (const float*)d_in[0];
  const int*   seqlen    = (const int*)  d_in[1];
  const int*   num_src   = (const int*)  d_in[2];
  const int*   num_dst   = (const int*)  d_in[3];
  const int*   num_pdf   = (const int*)  d_in[4];
  const float* num_w     = (const float*)d_in[5];
  const float* num_init  = (const float*)d_in[6];
  const float* num_final = (const float*)d_in[7];
  const int*   den_src   = (const int*)  d_in[8];
  const int*   den_dst   = (const int*)  d_in[9];
  const int*   den_pdf   = (const int*)  d_in[10];
  const float* den_w     = (const float*)d_in[11];
  const float* den_init  = (const float*)d_in[12];
  const float* den_final = (const float*)d_in[13];

  const int B     = in_sizes[1];
  const int A_num = in_sizes[2] / B;
  const int S_num = in_sizes[6];
  const int A_den = in_sizes[8];
  const int S_den = in_sizes[12];
  const int T     = 500;                       // problem spec
  const int C     = in_sizes[0] / (B * T);

  const int den_cap    = A_den + 3 * S_den + 64;
  const int num_stride = A_num + 3 * S_num + 64;

  // workspace layout
  size_t off = 0;
  auto alloc = [&](size_t bytes, size_t align) -> size_t {
    off = (off + align - 1) / align * align;
    size_t r = off; off += bytes; return r;
  };
  size_t o_den_meta = alloc((size_t)den_cap * 8, 16);
  size_t o_num_meta = alloc((size_t)B * num_stride * 8, 16);
  size_t o_den_rp   = alloc((size_t)2049 * 4, 4);
  size_t o_num_rp   = alloc((size_t)B * (S_num + 1) * 4, 4);
  size_t o_den_cnt  = alloc((size_t)S_den * 4, 4);
  size_t o_perm     = alloc((size_t)2048 * 4, 4);
  size_t o_inv      = alloc((size_t)S_den * 4, 4);
  size_t o_pc       = alloc((size_t)2048 * 4, 4);
  size_t o_num_pc   = alloc((size_t)B * S_num * 4, 4);
  size_t o_hist     = alloc((size_t)NCH * S_den * 4, 4);   // zeroed region start
  size_t o_num_cnt  = alloc((size_t)B * S_num * 4, 4);     // contiguous with hist
  size_t o_llh      = alloc((size_t)2 * B * 4, 4);
  const bool use_csr = (off <= ws_size) && (S_den >= 1) && (S_den <= 2048) &&
                       (S_num >= 1) && (S_num <= 2048) && (C <= MAX_C);

  char* wsb = (char*)d_ws;
  float* llh = (float*)(wsb + (use_csr ? o_llh : 0));

  if (use_csr) {
    uint2* den_meta = (uint2*)(wsb + o_den_meta);
    uint2* num_meta = (uint2*)(wsb + o_num_meta);
    int*   den_rp   = (int*)(wsb + o_den_rp);
    int*   num_rp   = (int*)(wsb + o_num_rp);
    int*   den_cnt  = (int*)(wsb + o_den_cnt);
    int*   perm     = (int*)(wsb + o_perm);
    int*   inv      = (int*)(wsb + o_inv);
    int*   pc       = (int*)(wsb + o_pc);
    int*   num_pc   = (int*)(wsb + o_num_pc);
    int*   hist     = (int*)(wsb + o_hist);
    int*   num_cnt  = (int*)(wsb + o_num_cnt);

    const int chunk = (A_den + NCH - 1) / NCH;

    // zero hist + num_cnt (contiguous)
    int ztot = NCH * S_den + B * S_num;
    zero_kernel<<<(ztot + 255) / 256, 256, 0, stream>>>(hist, ztot);

    hist_chunk_kernel<<<NCH, 256, 0, stream>>>(den_dst, A_den, chunk, S_den, hist);
    hist_kernel<<<dim3((A_num + 255) / 256, B), 256, 0, stream>>>(num_dst, A_num, A_num,
                                                                  num_cnt, S_num);

    colsum_kernel<<<(S_den + 255) / 256, 256, 0, stream>>>(hist, NCH, S_den, den_cnt);
    rank_perm_kernel<<<1, 1024, 0, stream>>>(den_cnt, S_den, perm, inv);
    pc_kernel<<<8, 256, 0, stream>>>(den_cnt, perm, S_den, pc);
    scan_kernel<<<1, 1024, 0, stream>>>(pc, den_rp, 2048);

    padcnt_kernel<<<(B * S_num + 255) / 256, 256, 0, stream>>>(num_cnt, B * S_num, num_pc);
    scan_kernel<<<B, 1024, 0, stream>>>(num_pc, num_rp, S_num);

    off_perm_kernel<<<(S_den + 255) / 256, 256, 0, stream>>>(hist, NCH, S_den, den_rp, perm);
    pad_den_kernel<<<(S_den + 255) / 256, 256, 0, stream>>>(den_rp, den_cnt, perm, S_den, den_meta);
    fill_chunk_kernel<<<dim3((S_den + 255) / 256, NCH), 256, 0, stream>>>(
        den_src, den_dst, den_pdf, den_w, A_den, chunk, S_den, hist, inv, den_meta);
    fill_kernel<<<dim3((S_num + 255) / 256, B), 256, 0, stream>>>(
        num_src, num_dst, num_pdf, num_w, A_num, A_num, num_rp, S_num, num_meta, num_stride);

    fsa_forward_lin<<<2 * B, 1024, 0, stream>>>(
        ll, seqlen, den_meta, den_rp, perm, S_den,
        num_meta, num_rp, num_stride, S_num,
        den_init, den_final, num_init, num_final, T, C, B, llh);
  } else {
    fsa_forward_fallback<<<2 * B, 1024, 0, stream>>>(
        ll, seqlen,
        den_src, den_dst, den_pdf, den_w, A_den, den_init, den_final, S_den,
        num_src, num_dst, num_pdf, num_w, A_num, num_init, num_final, S_num,
        T, C, B, llh);
  }

  final_loss_kernel<<<1, 64, 0, stream>>>(llh, B, (float*)d_out);
}

// Round 7
// 3461.419 us; speedup vs baseline: 1.3368x; 1.2754x over previous
//
#include <hip/hip_runtime.h>

#define NEG_INF_F (-1e30f)
#define MAX_S 2048
#define MAX_C 3008
#define NCH   128

// ============================ build helpers (deterministic) ============================

__global__ void zero_kernel(int* __restrict__ p, int n) {
  int i = blockIdx.x * blockDim.x + threadIdx.x;
  if (i < n) p[i] = 0;
}

__global__ void hist_kernel(const int* __restrict__ dst, int A, int A_stride,
                            int* __restrict__ cnt, int S) {
  int b = blockIdx.y;
  int i = blockIdx.x * blockDim.x + threadIdx.x;
  if (i < A) atomicAdd(&cnt[b * S + dst[(size_t)b * A_stride + i]], 1);
}

__global__ void hist_chunk_kernel(const int* __restrict__ dst, int A, int chunk, int S,
                                  int* __restrict__ hist) {
  int c = blockIdx.x;
  int i1 = min(A, (c + 1) * chunk);
  for (int i = c * chunk + threadIdx.x; i < i1; i += blockDim.x)
    atomicAdd(&hist[c * S + dst[i]], 1);
}

__global__ void colsum_kernel(const int* __restrict__ hist, int nch, int S,
                              int* __restrict__ cnt) {
  int s = blockIdx.x * blockDim.x + threadIdx.x;
  if (s < S) {
    int t = 0;
    for (int c = 0; c < nch; ++c) t += hist[c * S + s];
    cnt[s] = t;
  }
}

// Stable in-degree rank (desc) -> slot permutation pairing heavy with light.
__global__ __launch_bounds__(1024)
void rank_perm_kernel(const int* __restrict__ cnt, int S,
                      int* __restrict__ perm, int* __restrict__ invperm) {
  __shared__ int c[2048];
  __shared__ int R[2048];
  const int tid = threadIdx.x;
  for (int i = tid; i < 2048; i += 1024) c[i] = (i < S) ? cnt[i] : -1;
  __syncthreads();
  for (int u = 0; u < 2; ++u) {
    int s = tid + u * 1024;
    if (s < S) {
      int cs = c[s], r = 0;
      for (int j = 0; j < S; ++j) {
        int cj = c[j];
        r += (cj > cs) || (cj == cs && j < s);
      }
      R[r] = s;
    }
  }
  __syncthreads();
  for (int u = 0; u < 2; ++u) {
    int slot = tid + u * 1024;
    if (slot < S) {
      int state = (slot < 1024) ? R[slot] : R[S - 1 - (slot - 1024)];
      perm[slot] = state;
      invperm[state] = slot;
    }
  }
}

__global__ void pc_kernel(const int* __restrict__ cnt, const int* __restrict__ perm,
                          int S, int* __restrict__ pc) {
  int slot = blockIdx.x * blockDim.x + threadIdx.x;
  if (slot < 2048) pc[slot] = (slot < S) ? ((cnt[perm[slot]] + 3) & ~3) : 0;
}

__global__ void padcnt_kernel(const int* __restrict__ cnt, int n, int* __restrict__ out) {
  int i = blockIdx.x * blockDim.x + threadIdx.x;
  if (i < n) out[i] = (cnt[i] + 3) & ~3;
}

__global__ __launch_bounds__(1024) void scan_kernel(const int* __restrict__ cnt,
                                                    int* __restrict__ rp, int S) {
  __shared__ int buf[2][2048];
  const int tid = threadIdx.x;
  const int b = blockIdx.x;
  const int* c = cnt + (size_t)b * S;
  int* r = rp + (size_t)b * (S + 1);
  for (int u = 0; u < 2; ++u) {
    int i = tid + u * 1024;
    buf[0][i] = (i < S) ? c[i] : 0;
  }
  __syncthreads();
  int cur = 0;
  for (int off = 1; off < 2048; off <<= 1) {
    for (int u = 0; u < 2; ++u) {
      int i = tid + u * 1024;
      buf[cur ^ 1][i] = buf[cur][i] + ((i >= off) ? buf[cur][i - off] : 0);
    }
    __syncthreads();
    cur ^= 1;
  }
  for (int u = 0; u < 2; ++u) {
    int i = tid + u * 1024;
    if (i <= S) r[i] = (i == 0) ? 0 : buf[cur][i - 1];
  }
  if (tid == 0) r[S] = buf[cur][S - 1];
}

__global__ void off_perm_kernel(int* __restrict__ hist, int nch, int S,
                                const int* __restrict__ rp, const int* __restrict__ perm) {
  int slot = blockIdx.x * blockDim.x + threadIdx.x;
  if (slot < S) {
    int state = perm[slot];
    int run = rp[slot];
    for (int c = 0; c < nch; ++c) {
      int h = hist[c * S + state];
      hist[c * S + state] = run;
      run += h;
    }
  }
}

// fill pad arcs at row tails (den): ew = 0 -> term contributes nothing
__global__ void pad_den_kernel(const int* __restrict__ rp, const int* __restrict__ cnt,
                               const int* __restrict__ perm, int S, uint2* __restrict__ meta) {
  int slot = blockIdx.x * blockDim.x + threadIdx.x;
  if (slot < S) {
    int p = rp[slot] + cnt[perm[slot]];
    int e = rp[slot + 1];
    uint2 pad = make_uint2(0u, 0u);
    for (; p < e; ++p) meta[p] = pad;
  }
}

// DEN meta stores exp(w) (linear-space weight), src rewritten to slot space.
__global__ void fill_chunk_kernel(const int* __restrict__ src, const int* __restrict__ dst,
                                  const int* __restrict__ pdf, const float* __restrict__ w,
                                  int A, int chunk, int S, int* __restrict__ hoff,
                                  const int* __restrict__ inv, uint2* __restrict__ meta) {
  int c = blockIdx.y;
  int s = blockIdx.x * blockDim.x + threadIdx.x;
  if (s >= S) return;
  int i1 = min(A, (c + 1) * chunk);
  int p = hoff[c * S + s];
  for (int i = c * chunk; i < i1; ++i) {
    if (dst[i] == s) {
      meta[p++] = make_uint2((unsigned)inv[src[i]] | ((unsigned)pdf[i] << 16),
                             __float_as_uint(__expf(w[i])));
    }
  }
}

__global__ void fill_kernel(const int* __restrict__ src, const int* __restrict__ dst,
                            const int* __restrict__ pdf, const float* __restrict__ w,
                            int A, int A_stride, const int* __restrict__ rp, int S,
                            uint2* __restrict__ meta, int meta_stride) {
  int b = blockIdx.y;
  int s = blockIdx.x * blockDim.x + threadIdx.x;
  if (s >= S) return;
  const int*   sb = src + (size_t)b * A_stride;
  const int*   db = dst + (size_t)b * A_stride;
  const int*   pb = pdf + (size_t)b * A_stride;
  const float* wb = w   + (size_t)b * A_stride;
  const int*   rpb = rp + (size_t)b * (S + 1);
  uint2* mb = meta + (size_t)b * meta_stride;
  int p = rpb[s];
  for (int i = 0; i < A; ++i) {
    if (db[i] == s) {
      mb[p++] = make_uint2((unsigned)sb[i] | ((unsigned)pb[i] << 16), __float_as_uint(wb[i]));
    }
  }
  uint2 pad = make_uint2(0u, __float_as_uint(NEG_INF_F));
  int e = rpb[s + 1];
  for (; p < e; ++p) mb[p] = pad;
}

// ---- wave-interleaved den meta: desc = offA[16],offB[16],wmaxA[16],wmaxB[16],ok,total ----
__global__ __launch_bounds__(1024)
void wave_desc_kernel(const int* __restrict__ rp, int cap4, int* __restrict__ desc) {
  __shared__ int wm[32];
  const int tid = threadIdx.x;
  const int w = tid >> 6;
  int cA = (rp[tid + 1] - rp[tid]) >> 2;
  int sB = 2047 - tid;
  int cB = (rp[sB + 1] - rp[sB]) >> 2;
  for (int off = 32; off; off >>= 1) {
    cA = max(cA, __shfl_down(cA, off));
    cB = max(cB, __shfl_down(cB, off));
  }
  if ((tid & 63) == 0) { wm[w] = cA; wm[16 + w] = cB; }
  __syncthreads();
  if (tid == 0) {
    int off = 0;
    for (int i = 0; i < 16; ++i) { desc[i] = off; off += wm[i] * 128; }
    for (int i = 0; i < 16; ++i) { desc[16 + i] = off; off += wm[16 + i] * 128; }
    for (int i = 0; i < 16; ++i) { desc[32 + i] = wm[i]; desc[48 + i] = wm[16 + i]; }
    desc[64] = (off <= cap4) ? 1 : 0;
    desc[65] = off;
  }
}

// grid 32 blocks x 64 lanes: block<16 -> A wave, else B wave. Chunk-interleaved copy.
__global__ void repack_kernel(const uint2* __restrict__ meta, const int* __restrict__ rp,
                              const int* __restrict__ desc, uint2* __restrict__ ilv) {
  if (!desc[64]) return;
  const int w = blockIdx.x & 15;
  const bool isB = blockIdx.x >= 16;
  const int l = threadIdx.x;
  const int tid = w * 64 + l;
  const int s = isB ? (2047 - tid) : tid;
  const int base4 = desc[(isB ? 16 : 0) + w];
  const int wmax  = desc[(isB ? 48 : 32) + w];
  const int r0 = rp[s];
  const int n = (rp[s + 1] - r0) >> 2;
  for (int c = 0; c < wmax; ++c) {
    for (int part = 0; part < 2; ++part) {
      int u4 = base4 + c * 128 + part * 64 + l;
      uint2 v0 = make_uint2(0u, 0u), v1 = make_uint2(0u, 0u);
      if (c < n) {
        v0 = meta[r0 + 4 * c + 2 * part];
        v1 = meta[r0 + 4 * c + 2 * part + 1];
      }
      ilv[2 * u4]     = v0;
      ilv[2 * u4 + 1] = v1;
    }
  }
}

// ============================ exact row LSE (numerator path) ============================

__device__ __forceinline__ float row_lse(const uint2* __restrict__ meta, int k, int e,
                                         const float* __restrict__ alpha,
                                         const float* __restrict__ lcur) {
  float mm0 = NEG_INF_F, ss0 = 0.0f, mm1 = NEG_INF_F, ss1 = 0.0f;
  const int n4 = (e - k) >> 2;
  const uint4* p = (const uint4*)(meta + k);
  if (n4 > 0) {
    uint4 A = p[0], Bv = p[1];
    float t0 = alpha[A.x & 0xFFFFu] + __uint_as_float(A.y) + lcur[A.x >> 16];
    float t1 = alpha[A.z & 0xFFFFu] + __uint_as_float(A.w) + lcur[A.z >> 16];
    float t2 = alpha[Bv.x & 0xFFFFu] + __uint_as_float(Bv.y) + lcur[Bv.x >> 16];
    float t3 = alpha[Bv.z & 0xFFFFu] + __uint_as_float(Bv.w) + lcur[Bv.z >> 16];
    for (int c2 = 1; c2 < n4; ++c2) {
      uint4 A2 = p[2 * c2], B2 = p[2 * c2 + 1];
      float u0 = alpha[A2.x & 0xFFFFu] + __uint_as_float(A2.y) + lcur[A2.x >> 16];
      float u1 = alpha[A2.z & 0xFFFFu] + __uint_as_float(A2.w) + lcur[A2.z >> 16];
      float u2 = alpha[B2.x & 0xFFFFu] + __uint_as_float(B2.y) + lcur[B2.x >> 16];
      float u3 = alpha[B2.z & 0xFFFFu] + __uint_as_float(B2.w) + lcur[B2.z >> 16];
      float mc = fmaxf(fmaxf(t0, t1), fmaxf(t2, t3));
      if ((c2 & 1) != 0) {
        float nm = fmaxf(mm0, mc);
        ss0 = ss0 * __expf(mm0 - nm) +
              ((__expf(t0 - nm) + __expf(t1 - nm)) + (__expf(t2 - nm) + __expf(t3 - nm)));
        mm0 = nm;
      } else {
        float nm = fmaxf(mm1, mc);
        ss1 = ss1 * __expf(mm1 - nm) +
              ((__expf(t0 - nm) + __expf(t1 - nm)) + (__expf(t2 - nm) + __expf(t3 - nm)));
        mm1 = nm;
      }
      t0 = u0; t1 = u1; t2 = u2; t3 = u3;
    }
    float mc = fmaxf(fmaxf(t0, t1), fmaxf(t2, t3));
    if ((n4 & 1) != 0) {
      float nm = fmaxf(mm0, mc);
      ss0 = ss0 * __expf(mm0 - nm) +
            ((__expf(t0 - nm) + __expf(t1 - nm)) + (__expf(t2 - nm) + __expf(t3 - nm)));
      mm0 = nm;
    } else {
      float nm = fmaxf(mm1, mc);
      ss1 = ss1 * __expf(mm1 - nm) +
            ((__expf(t0 - nm) + __expf(t1 - nm)) + (__expf(t2 - nm) + __expf(t3 - nm)));
      mm1 = nm;
    }
  }
  float nm = fmaxf(mm0, mm1);
  float ssc = ss0 * __expf(mm0 - nm) + ss1 * __expf(mm1 - nm);
  return (ssc > 0.0f) ? (__logf(ssc) + nm) : NEG_INF_F;
}

__device__ __forceinline__ void stage_row(const float* __restrict__ row,
                                          float* __restrict__ lds, int C, int tid, int nt) {
  if (((C & 3) == 0) && ((((uintptr_t)row) & 15) == 0)) {
    const float4* r4 = (const float4*)row;
    const int n = C >> 2;
    for (int i = tid; i < n; i += nt) ((float4*)lds)[i] = r4[i];
  } else {
    for (int i = tid; i < C; i += nt) lds[i] = row[i];
  }
}

#define ACC4(X, Y, s0, s1, s2, s3)                                                       \
  s0 = fmaf(__uint_as_float((X).y), vbuf[(X).x & 0xFFFFu] * elbuf[(X).x >> 16], s0);     \
  s1 = fmaf(__uint_as_float((X).w), vbuf[(X).z & 0xFFFFu] * elbuf[(X).z >> 16], s1);     \
  s2 = fmaf(__uint_as_float((Y).y), vbuf[(Y).x & 0xFFFFu] * elbuf[(Y).x >> 16], s2);     \
  s3 = fmaf(__uint_as_float((Y).w), vbuf[(Y).z & 0xFFFFu] * elbuf[(Y).z >> 16], s3);

// ============================ forward: den linear-space (interleaved meta), num exact-LSE ============================
__global__ __launch_bounds__(1024, 4)
void fsa_forward_lin(const float* __restrict__ ll, const int* __restrict__ seqlen,
                     const uint2* __restrict__ den_meta, const uint4* __restrict__ den_ilv,
                     const int* __restrict__ den_desc,
                     const int* __restrict__ den_rp, const int* __restrict__ den_perm, int S_den,
                     const uint2* __restrict__ num_meta, const int* __restrict__ num_rp,
                     int num_stride, int S_num,
                     const float* __restrict__ den_init, const float* __restrict__ den_final,
                     const float* __restrict__ num_init, const float* __restrict__ num_final,
                     int T, int C, int B, float* __restrict__ out_llh)
{
  __shared__ float alpha[MAX_S];
  __shared__ float vbuf[MAX_S];
  __shared__ float elbuf[MAX_C];   // den: exp(ll) ; num: raw ll
  __shared__ float red[16];
  __shared__ int   sdesc[66];

  const int tid = threadIdx.x;
  const int nt  = 1024;
  const bool is_den = ((int)blockIdx.x) < B;
  const int b = is_den ? (int)blockIdx.x : ((int)blockIdx.x - B);
  const int S = is_den ? S_den : S_num;
  const float* fin  = is_den ? den_final : num_final;
  const int*   perm = is_den ? den_perm  : nullptr;

  const int L = seqlen[b];
  const float* llb = ll + ((size_t)b * T) * C;

  if (is_den) {
    // ---- linear-space denominator ----
    for (int i = tid; i < 66; i += nt) sdesc[i] = den_desc[i];

    const int w = tid >> 6, l = tid & 63;
    const int slotA = tid;            // heavy ranks
    const int slotB = 2047 - tid;     // paired light ranks
    const int rA0 = den_rp[slotA], rA1 = den_rp[slotA + 1];
    const int rB0 = den_rp[slotB], rB1 = den_rp[slotB + 1];
    float a0 = (slotA < S) ? den_init[den_perm[slotA]] : NEG_INF_F;
    float a1 = (slotB < S) ? den_init[den_perm[slotB]] : NEG_INF_F;

    const int nvec = C >> 2;
    const bool pf = ((C & 3) == 0) && ((((uintptr_t)llb) & 15) == 0) &&
                    (nvec <= nt) && (C <= MAX_C);

    // initial M reduce + EL stage for row 0
    float lm = fmaxf(a0, a1);
    for (int off = 32; off; off >>= 1) lm = fmaxf(lm, __shfl_down(lm, off));
    if ((tid & 63) == 0) red[tid >> 6] = lm;
    if (L > 0) {
      if (pf) {
        if (tid < nvec) {
          float4 r = ((const float4*)llb)[tid];
          elbuf[4 * tid + 0] = __expf(r.x); elbuf[4 * tid + 1] = __expf(r.y);
          elbuf[4 * tid + 2] = __expf(r.z); elbuf[4 * tid + 3] = __expf(r.w);
        }
      } else {
        for (int i = tid; i < C; i += nt) elbuf[i] = __expf(llb[i]);
      }
    }
    __syncthreads();
    float M = red[0];
#pragma unroll
    for (int i = 1; i < 16; ++i) M = fmaxf(M, red[i]);

    const bool ilv_ok = sdesc[64] != 0;
    const uint4* pA4 = den_ilv + sdesc[w] + l;
    const uint4* pB4 = den_ilv + sdesc[16 + w] + l;
    const int nA = sdesc[32 + w], nB = sdesc[48 + w];

    for (int t = 0; t < L; ++t) {
      vbuf[slotA] = __expf(a0 - M);
      vbuf[slotB] = __expf(a1 - M);
      __syncthreads();                       // v + EL ready

      float4 nx;
      const bool donx = pf && (t + 1 < L) && (tid < nvec);
      if (donx) nx = ((const float4*)(llb + (size_t)(t + 1) * C))[tid];

      float sA0 = 0, sA1 = 0, sA2 = 0, sA3 = 0;
      float sB0 = 0, sB1 = 0, sB2 = 0, sB3 = 0;
      if (ilv_ok) {
        // ---- wave-uniform interleaved loops, coalesced meta, 2-deep prefetch ----
        if (nA > 0) {
          uint4 X0 = pA4[0], Y0 = pA4[64];
          if (nA > 1) {
            uint4 X1 = pA4[128], Y1 = pA4[192];
            for (int c = 2; c < nA; ++c) {
              uint4 X2 = pA4[c * 128], Y2 = pA4[c * 128 + 64];
              ACC4(X0, Y0, sA0, sA1, sA2, sA3);
              X0 = X1; Y0 = Y1; X1 = X2; Y1 = Y2;
            }
            ACC4(X0, Y0, sA0, sA1, sA2, sA3);
            X0 = X1; Y0 = Y1;
          }
          ACC4(X0, Y0, sA0, sA1, sA2, sA3);
        }
        if (nB > 0) {
          uint4 X0 = pB4[0], Y0 = pB4[64];
          for (int c = 1; c < nB; ++c) {
            uint4 X1 = pB4[c * 128], Y1 = pB4[c * 128 + 64];
            ACC4(X0, Y0, sB0, sB1, sB2, sB3);
            X0 = X1; Y0 = Y1;
          }
          ACC4(X0, Y0, sB0, sB1, sB2, sB3);
        }
      } else {
        // ---- fallback: row-major guarded interleave (round-6 path) ----
        const uint4* pA = (const uint4*)(den_meta + rA0);
        const uint4* pB = (const uint4*)(den_meta + rB0);
        const int nAr = (rA1 - rA0) >> 2, nBr = (rB1 - rB0) >> 2;
        const int n = nAr > nBr ? nAr : nBr;
        for (int c = 0; c < n; ++c) {
          if (c < nAr) {
            uint4 X = pA[2 * c], Y = pA[2 * c + 1];
            ACC4(X, Y, sA0, sA1, sA2, sA3);
          }
          if (c < nBr) {
            uint4 X = pB[2 * c], Y = pB[2 * c + 1];
            ACC4(X, Y, sB0, sB1, sB2, sB3);
          }
        }
      }
      float sA = (sA0 + sA1) + (sA2 + sA3);
      float sB = (sB0 + sB1) + (sB2 + sB3);
      __syncthreads();                       // done reading vbuf/elbuf

      a0 = (sA > 0.0f) ? (__logf(sA) + M) : NEG_INF_F;
      a1 = (sB > 0.0f) ? (__logf(sB) + M) : NEG_INF_F;

      if (donx) {
        elbuf[4 * tid + 0] = __expf(nx.x); elbuf[4 * tid + 1] = __expf(nx.y);
        elbuf[4 * tid + 2] = __expf(nx.z); elbuf[4 * tid + 3] = __expf(nx.w);
      } else if (!pf && t + 1 < L) {
        const float* nr = llb + (size_t)(t + 1) * C;
        for (int i = tid; i < C; i += nt) elbuf[i] = __expf(nr[i]);
      }

      float lm2 = fmaxf(a0, a1);
      for (int off = 32; off; off >>= 1) lm2 = fmaxf(lm2, __shfl_down(lm2, off));
      if ((tid & 63) == 0) red[tid >> 6] = lm2;
      __syncthreads();                       // red + next EL visible
      M = red[0];
#pragma unroll
      for (int i = 1; i < 16; ++i) M = fmaxf(M, red[i]);
    }
    alpha[slotA] = a0;
    alpha[slotB] = a1;
    __syncthreads();
  } else {
    // ---- exact-LSE numerator (tiny) ----
    const uint2* meta = num_meta + (size_t)b * num_stride;
    const int*   rp   = num_rp + (size_t)b * (S_num + 1);
    for (int s = tid; s < MAX_S; s += nt) alpha[s] = (s < S) ? num_init[s] : NEG_INF_F;
    int rs[2] = {0, 0}, re[2] = {0, 0};
    for (int u = 0; u < 2; ++u) {
      int s = tid + u * nt;
      if (s < S) { rs[u] = rp[s]; re[u] = rp[s + 1]; }
    }
    __syncthreads();
    for (int t = 0; t < L; ++t) {
      stage_row(llb + (size_t)t * C, elbuf, C, tid, nt);
      __syncthreads();
      float nv[2];
      for (int u = 0; u < 2; ++u) {
        int s = tid + u * nt;
        nv[u] = (s < S) ? row_lse(meta, rs[u], re[u], alpha, elbuf) : NEG_INF_F;
      }
      __syncthreads();
      for (int u = 0; u < 2; ++u) {
        int s = tid + u * nt;
        if (s < S) alpha[s] = nv[u];
      }
      __syncthreads();
    }
  }

  // final logsumexp(alpha + final_logp)
  float lm = -3.0e38f;
  for (int s = tid; s < S; s += nt) lm = fmaxf(lm, alpha[s] + fin[perm ? perm[s] : s]);
  for (int off = 32; off; off >>= 1) lm = fmaxf(lm, __shfl_down(lm, off));
  if ((tid & 63) == 0) red[tid >> 6] = lm;
  __syncthreads();
  if (tid < 64) {
    float v = (tid < 16) ? red[tid] : -3.0e38f;
    for (int off = 32; off; off >>= 1) v = fmaxf(v, __shfl_down(v, off));
    if (tid == 0) red[0] = v;
  }
  __syncthreads();
  const float M = red[0];

  float ls = 0.0f;
  for (int s = tid; s < S; s += nt) ls += __expf(alpha[s] + fin[perm ? perm[s] : s] - M);
  for (int off = 32; off; off >>= 1) ls += __shfl_down(ls, off);
  __syncthreads();
  if ((tid & 63) == 0) red[tid >> 6] = ls;
  __syncthreads();
  if (tid < 64) {
    float v = (tid < 16) ? red[tid] : 0.0f;
    for (int off = 32; off; off >>= 1) v += __shfl_down(v, off);
    if (tid == 0) out_llh[(is_den ? 0 : B) + b] = __logf(v) + M;
  }
}

// ============================ fallback (atomic path, tiny ws) ============================

__device__ __forceinline__ unsigned enc_f(float x) {
  unsigned u = __float_as_uint(x);
  return u ^ (unsigned)(((int)u >> 31) | 0x80000000);
}
__device__ __forceinline__ float dec_f(unsigned e) {
  unsigned mask = ((int)e >= 0) ? 0xFFFFFFFFu : 0x80000000u;
  return __uint_as_float(e ^ mask);
}

__global__ __launch_bounds__(1024)
void fsa_forward_fallback(
    const float* __restrict__ ll, const int* __restrict__ seqlen,
    const int* __restrict__ den_src, const int* __restrict__ den_dst,
    const int* __restrict__ den_pdf, const float* __restrict__ den_w,
    int A_den, const float* __restrict__ den_init, const float* __restrict__ den_final, int S_den,
    const int* __restrict__ num_src, const int* __restrict__ num_dst,
    const int* __restrict__ num_pdf, const float* __restrict__ num_w,
    int A_num, const float* __restrict__ num_init, const float* __restrict__ num_final, int S_num,
    int T, int C, int B, float* __restrict__ out_llh)
{
  __shared__ float    alpha[MAX_S];
  __shared__ unsigned menc[MAX_S];
  __shared__ float    msafe[MAX_S];
  __shared__ float    ssum[MAX_S];
  __shared__ float    llrow[MAX_C];

  const int tid = threadIdx.x;
  const int nt  = blockDim.x;
  const bool is_den = ((int)blockIdx.x) < B;
  const int b = is_den ? (int)blockIdx.x : ((int)blockIdx.x - B);
  const int S = is_den ? S_den : S_num;
  const int A = is_den ? A_den : A_num;
  const float* init = is_den ? den_init  : num_init;
  const float* fin  = is_den ? den_final : num_final;
  const int*   asrc = is_den ? den_src  : (num_src + (size_t)b * A_num);
  const int*   adst = is_den ? den_dst  : (num_dst + (size_t)b * A_num);
  const int*   apdf = is_den ? den_pdf  : (num_pdf + (size_t)b * A_num);
  const float* aw   = is_den ? den_w    : (num_w   + (size_t)b * A_num);

  for (int s = tid; s < S; s += nt) { alpha[s] = init[s]; menc[s] = 0u; ssum[s] = 0.0f; }
  __syncthreads();

  const int L = seqlen[b];
  const float* llb = ll + ((size_t)b * T) * C;

  for (int t = 0; t < L; ++t) {
    const float* row = llb + (size_t)t * C;
    for (int i = tid; i < C; i += nt) llrow[i] = row[i];
    __syncthreads();
    for (int i = tid; i < A; i += nt) {
      float score = alpha[asrc[i]] + aw[i] + llrow[apdf[i]];
      atomicMax(&menc[adst[i]], enc_f(score));
    }
    __syncthreads();
    for (int s = tid; s < S; s += nt) {
      float m = dec_f(menc[s]);
      msafe[s] = (m > -5e29f) ? m : 0.0f;
    }
    __syncthreads();
    for (int i = tid; i < A; i += nt) {
      int d = adst[i];
      float score = alpha[asrc[i]] + aw[i] + llrow[apdf[i]];
      atomicAdd(&ssum[d], __expf(score - msafe[d]));
    }
    __syncthreads();
    for (int s = tid; s < S; s += nt) {
      float sum = ssum[s];
      alpha[s] = (sum > 0.0f) ? (__logf(sum) + msafe[s]) : NEG_INF_F;
      menc[s] = 0u; ssum[s] = 0.0f;
    }
    __syncthreads();
  }

  float lm = -3.0e38f;
  for (int s = tid; s < S; s += nt) lm = fmaxf(lm, alpha[s] + fin[s]);
  for (int off = 32; off; off >>= 1) lm = fmaxf(lm, __shfl_down(lm, off));
  const int nwaves = nt >> 6;
  if ((tid & 63) == 0) msafe[tid >> 6] = lm;
  __syncthreads();
  if (tid < 64) {
    float v = (tid < nwaves) ? msafe[tid] : -3.0e38f;
    for (int off = 32; off; off >>= 1) v = fmaxf(v, __shfl_down(v, off));
    if (tid == 0) msafe[MAX_S - 1] = v;
  }
  __syncthreads();
  const float M = msafe[MAX_S - 1];
  float ls = 0.0f;
  for (int s = tid; s < S; s += nt) ls += __expf(alpha[s] + fin[s] - M);
  for (int off = 32; off; off >>= 1) ls += __shfl_down(ls, off);
  if ((tid & 63) == 0) ssum[tid >> 6] = ls;
  __syncthreads();
  if (tid < 64) {
    float v = (tid < nwaves) ? ssum[tid] : 0.0f;
    for (int off = 32; off; off >>= 1) v += __shfl_down(v, off);
    if (tid == 0) out_llh[(is_den ? 0 : B) + b] = __logf(v) + M;
  }
}

// loss = sum_b (den_llh[b] - num_llh[b])
__global__ void final_loss_kernel(const float* __restrict__ llh, int B, float* __restrict__ out) {
  int lane = threadIdx.x;
  float v = (lane < B) ? (llh[lane] - llh[B + lane]) : 0.0f;
  for (int off = 32; off; off >>= 1) v += __shfl_down(v, off);
  if (lane == 0) out[0] = v;
}

extern "C" void kernel_launch(void* const* d_in, const int* in_sizes, int n_in,
                              void* d_out, int out_size, void* d_ws, size_t ws_size,
                              hipStream_t stream) {
  const float* ll        = (const float*)d_in[0];
  const int*   seqlen    = (const int*)  d_in[1];
  const int*   num_src   = (const int*)  d_in[2];
  const int*   num_dst   = (const int*)  d_in[3];
  const int*   num_pdf   = (const int*)  d_in[4];
  const float* num_w     = (const float*)d_in[5];
  const float* num_init  = (const float*)d_in[6];
  const float* num_final = (const float*)d_in[7];
  const int*   den_src   = (const int*)  d_in[8];
  const int*   den_dst   = (const int*)  d_in[9];
  const int*   den_pdf   = (const int*)  d_in[10];
  const float* den_w     = (const float*)d_in[11];
  const float* den_init  = (const float*)d_in[12];
  const float* den_final = (const float*)d_in[13];

  const int B     = in_sizes[1];
  const int A_num = in_sizes[2] / B;
  const int S_num = in_sizes[6];
  const int A_den = in_sizes[8];
  const int S_den = in_sizes[12];
  const int T     = 500;                       // problem spec
  const int C     = in_sizes[0] / (B * T);

  const int den_cap    = A_den + 3 * S_den + 64;
  const int num_stride = A_num + 3 * S_num + 64;
  const int cap4       = den_cap + 32768;      // interleaved capacity (uint4 units, ~2x need)

  // workspace layout
  size_t off = 0;
  auto alloc = [&](size_t bytes, size_t align) -> size_t {
    off = (off + align - 1) / align * align;
    size_t r = off; off += bytes; return r;
  };
  size_t o_den_meta = alloc((size_t)den_cap * 8, 16);
  size_t o_den_ilv  = alloc((size_t)cap4 * 16, 16);
  size_t o_desc     = alloc((size_t)66 * 4, 4);
  size_t o_num_meta = alloc((size_t)B * num_stride * 8, 16);
  size_t o_den_rp   = alloc((size_t)2049 * 4, 4);
  size_t o_num_rp   = alloc((size_t)B * (S_num + 1) * 4, 4);
  size_t o_den_cnt  = alloc((size_t)S_den * 4, 4);
  size_t o_perm     = alloc((size_t)2048 * 4, 4);
  size_t o_inv      = alloc((size_t)S_den * 4, 4);
  size_t o_pc       = alloc((size_t)2048 * 4, 4);
  size_t o_num_pc   = alloc((size_t)B * S_num * 4, 4);
  size_t o_hist     = alloc((size_t)NCH * S_den * 4, 4);   // zeroed region start
  size_t o_num_cnt  = alloc((size_t)B * S_num * 4, 4);     // contiguous with hist
  size_t o_llh      = alloc((size_t)2 * B * 4, 4);
  const bool use_csr = (off <= ws_size) && (S_den >= 1) && (S_den <= 2048) &&
                       (S_num >= 1) && (S_num <= 2048) && (C <= MAX_C);

  char* wsb = (char*)d_ws;
  float* llh = (float*)(wsb + (use_csr ? o_llh : 0));

  if (use_csr) {
    uint2* den_meta = (uint2*)(wsb + o_den_meta);
    uint4* den_ilv  = (uint4*)(wsb + o_den_ilv);
    int*   desc     = (int*)(wsb + o_desc);
    uint2* num_meta = (uint2*)(wsb + o_num_meta);
    int*   den_rp   = (int*)(wsb + o_den_rp);
    int*   num_rp   = (int*)(wsb + o_num_rp);
    int*   den_cnt  = (int*)(wsb + o_den_cnt);
    int*   perm     = (int*)(wsb + o_perm);
    int*   inv      = (int*)(wsb + o_inv);
    int*   pc       = (int*)(wsb + o_pc);
    int*   num_pc   = (int*)(wsb + o_num_pc);
    int*   hist     = (int*)(wsb + o_hist);
    int*   num_cnt  = (int*)(wsb + o_num_cnt);

    const int chunk = (A_den + NCH - 1) / NCH;

    // zero hist + num_cnt (contiguous)
    int ztot = NCH * S_den + B * S_num;
    zero_kernel<<<(ztot + 255) / 256, 256, 0, stream>>>(hist, ztot);

    hist_chunk_kernel<<<NCH, 256, 0, stream>>>(den_dst, A_den, chunk, S_den, hist);
    hist_kernel<<<dim3((A_num + 255) / 256, B), 256, 0, stream>>>(num_dst, A_num, A_num,
                                                                  num_cnt, S_num);

    colsum_kernel<<<(S_den + 255) / 256, 256, 0, stream>>>(hist, NCH, S_den, den_cnt);
    rank_perm_kernel<<<1, 1024, 0, stream>>>(den_cnt, S_den, perm, inv);
    pc_kernel<<<8, 256, 0, stream>>>(den_cnt, perm, S_den, pc);
    scan_kernel<<<1, 1024, 0, stream>>>(pc, den_rp, 2048);
    wave_desc_kernel<<<1, 1024, 0, stream>>>(den_rp, cap4, desc);

    padcnt_kernel<<<(B * S_num + 255) / 256, 256, 0, stream>>>(num_cnt, B * S_num, num_pc);
    scan_kernel<<<B, 1024, 0, stream>>>(num_pc, num_rp, S_num);

    off_perm_kernel<<<(S_den + 255) / 256, 256, 0, stream>>>(hist, NCH, S_den, den_rp, perm);
    pad_den_kernel<<<(S_den + 255) / 256, 256, 0, stream>>>(den_rp, den_cnt, perm, S_den, den_meta);
    fill_chunk_kernel<<<dim3((S_den + 255) / 256, NCH), 256, 0, stream>>>(
        den_src, den_dst, den_pdf, den_w, A_den, chunk, S_den, hist, inv, den_meta);
    fill_kernel<<<dim3((S_num + 255) / 256, B), 256, 0, stream>>>(
        num_src, num_dst, num_pdf, num_w, A_num, A_num, num_rp, S_num, num_meta, num_stride);

    repack_kernel<<<32, 64, 0, stream>>>(den_meta, den_rp, desc, (uint2*)den_ilv);

    fsa_forward_lin<<<2 * B, 1024, 0, stream>>>(
        ll, seqlen, den_meta, den_ilv, desc, den_rp, perm, S_den,
        num_meta, num_rp, num_stride, S_num,
        den_init, den_final, num_init, num_final, T, C, B, llh);
  } else {
    fsa_forward_fallback<<<2 * B, 1024, 0, stream>>>(
        ll, seqlen,
        den_src, den_dst, den_pdf, den_w, A_den, den_init, den_final, S_den,
        num_src, num_dst, num_pdf, num_w, A_num, num_init, num_final, S_num,
        T, C, B, llh);
  }

  final_loss_kernel<<<1, 64, 0, stream>>>(llh, B, (float*)d_out);
}